// Round 3
// baseline (771.844 us; speedup 1.0000x reference)
//
#include <hip/hip_runtime.h>

typedef __bf16 bf16x8 __attribute__((ext_vector_type(8)));
typedef float  f32x4  __attribute__((ext_vector_type(4)));

__device__ __forceinline__ bf16x8 ldb8(const __bf16* p) {
    return *reinterpret_cast<const bf16x8*>(p);
}
__device__ __forceinline__ bf16x8 zero8() {
    bf16x8 z;
    #pragma unroll
    for (int i = 0; i < 8; i++) z[i] = (__bf16)0.f;
    return z;
}
// mode m: 0 = storage is bf16, 1 = storage is fp32
__device__ __forceinline__ __bf16 ldw(const void* p, int i, int m) {
    return m ? (__bf16)((const float*)p)[i] : ((const __bf16*)p)[i];
}
__device__ __forceinline__ bf16x8 ldx8(const void* p, size_t ei, int m) {
    if (m) {
        const float* f = (const float*)p + ei;
        f32x4 a = *reinterpret_cast<const f32x4*>(f);
        f32x4 b = *reinterpret_cast<const f32x4*>(f + 4);
        bf16x8 r;
        #pragma unroll
        for (int u = 0; u < 4; u++) { r[u] = (__bf16)a[u]; r[4 + u] = (__bf16)b[u]; }
        return r;
    }
    return ldb8((const __bf16*)p + ei);
}

// ---------------- detect: input dtype + mask expand ----------------
__global__ __launch_bounds__(256) void detect_kernel(
    const void* x, const void* mask, int* modes, int* maskws)
{
    __shared__ int sbad, v32bad, v16bad;
    const int t = threadIdx.x;
    if (t == 0) { sbad = 0; v32bad = 0; v16bad = 0; }
    __syncthreads();
    const unsigned int* xw = (const unsigned int*)x;
    int bad = 0;
    for (int i = t; i < 2048; i += 256) {
        unsigned int w = xw[i];
        unsigned int el = (w >> 7) & 0xFF, eh = (w >> 23) & 0xFF;
        if (el >= 0x94 || el == 0xFF) bad++;
        if (eh >= 0x94 || eh == 0xFF) bad++;
    }
    if (bad) atomicAdd(&sbad, bad);
    const unsigned int* mw = (const unsigned int*)mask;
    int b32 = 0, b16 = 0;
    for (int i = t; i < 10496; i += 256) {
        unsigned int w = mw[i];
        if (!(w == 0u || w == 1u || w == 0x3F800000u)) b32++;
        unsigned int h0 = w & 0xFFFFu, h1 = w >> 16;
        if (!(h0 == 0u || h0 == 1u || h0 == 0x3F80u)) b16++;
        if (!(h1 == 0u || h1 == 1u || h1 == 0x3F80u)) b16++;
    }
    if (b32) atomicAdd(&v32bad, b32);
    if (b16) atomicAdd(&v16bad, b16);
    __syncthreads();
    const int mode_x = (sbad > 64) ? 1 : 0;
    const int mmode = (v32bad == 0) ? 0 : ((v16bad == 0) ? 2 : 1);
    if (t == 0) { modes[0] = mode_x; modes[1] = mmode; }
    for (int i = t; i < 41984; i += 256) {
        int val;
        if (mmode == 0)      val = (((const int*)mask)[i] != 0);
        else if (mmode == 2) val = (((const unsigned short*)mask)[i] != 0);
        else                 val = (((const unsigned char*)mask)[i] != 0);
        maskws[i] = val;
    }
}

// ---------------- prep: transpose/pad weights into ws (mode-aware) ----------------
// Wts/Wtq: (768 x 256)  rows 0..511 = w_qk^T (q|k), rows 512..767 = w_v^T
// w1t: (4 x 64 x 128)  w1[e]^T zero-padded (n<50, k<100)
// w2t: (4 x 112 x 64)  w2[e]^T zero-padded (n<100, k<50)
// wot: (256 x 256)     w_out^T
// wsm: [0:128)=w_gate [128:132)=b_gate [132:136)=ln_g [136:140)=ln_b
//      [140:340)=b1 [340:740)=b2 [740:996)=b_out
__global__ __launch_bounds__(256) void prep_kernel(
    const void* wqks, const void* wqkq, const void* wv, const void* w1,
    const void* w2, const void* wout, const void* wg, const void* bg,
    const void* lng, const void* lnb, const void* b1, const void* b2,
    const void* bout, const int* __restrict__ modes,
    __bf16* __restrict__ Wts, __bf16* __restrict__ Wtq,
    __bf16* __restrict__ w1t, __bf16* __restrict__ w2t,
    __bf16* __restrict__ wot, __bf16* __restrict__ wsm)
{
    const int m = modes[0];
    int i = blockIdx.x * 256 + threadIdx.x;
    if (i < 196608) {
        int n = i >> 8, k = i & 255;
        __bf16 vs, vq;
        if (n < 512) { vs = ldw(wqks, k * 512 + n, m); vq = ldw(wqkq, k * 512 + n, m); }
        else         { vs = ldw(wv, k * 256 + (n - 512), m); vq = vs; }
        Wts[i] = vs; Wtq[i] = vq;
        return;
    }
    i -= 196608;
    if (i < 32768) {
        int e = i >> 13, r = i & 8191, n = r >> 7, k = r & 127;
        w1t[i] = (n < 50 && k < 100) ? ldw(w1, (e * 100 + k) * 50 + n, m) : (__bf16)0.f;
        return;
    }
    i -= 32768;
    if (i < 28672) {
        int e = i / 7168, r = i % 7168, n = r >> 6, k = r & 63;
        w2t[i] = (n < 100 && k < 50) ? ldw(w2, (e * 50 + k) * 100 + n, m) : (__bf16)0.f;
        return;
    }
    i -= 28672;
    if (i < 65536) {
        int n = i >> 8, k = i & 255;
        wot[i] = ldw(wout, k * 256 + n, m);
        return;
    }
    i -= 65536;
    if (i < 996) {
        __bf16 v;
        if (i < 128)      v = ldw(wg, i, m);
        else if (i < 132) v = ldw(bg, i - 128, m);
        else if (i < 136) v = ldw(lng, i - 132, m);
        else if (i < 140) v = ldw(lnb, i - 136, m);
        else if (i < 340) v = ldw(b1, i - 140, m);
        else if (i < 740) v = ldw(b2, i - 340, m);
        else              v = ldw(bout, i - 740, m);
        wsm[i] = v;
    }
}

// ---------------- gates: g = gx@w_gate + b; LN; softmax ----------------
// gx[b,h,j,d] = x[b].flat[h*5248 + j*32 + d]  (raw reshape, NOT head split)
__global__ __launch_bounds__(128) void gate_kernel(
    const void* __restrict__ x, const __bf16* __restrict__ wsm,
    const int* __restrict__ modes, float* __restrict__ gates)
{
    __shared__ float wgs[128];
    __shared__ float bgs[4], gs[4], bs[4];
    const int bh = blockIdx.x, t = threadIdx.x;
    wgs[t] = (float)wsm[t];
    if (t < 4) { bgs[t] = (float)wsm[128 + t]; gs[t] = (float)wsm[132 + t]; bs[t] = (float)wsm[136 + t]; }
    __syncthreads();
    if (t >= 100) return;
    const int m = modes[0];
    const int b = bh >> 3, h = bh & 7;
    const size_t base = (size_t)b * 41984 + h * 5248 + t * 32;
    float g[4] = {bgs[0], bgs[1], bgs[2], bgs[3]};
    #pragma unroll
    for (int p = 0; p < 4; p++) {
        bf16x8 xv = ldx8(x, base + p * 8, m);
        #pragma unroll
        for (int u = 0; u < 8; u++) {
            float f = (float)xv[u];
            #pragma unroll
            for (int e = 0; e < 4; e++) g[e] += f * wgs[(p * 8 + u) * 4 + e];
        }
    }
    float mu = 0.25f * (g[0] + g[1] + g[2] + g[3]);
    float var = 0.25f * ((g[0]-mu)*(g[0]-mu) + (g[1]-mu)*(g[1]-mu) +
                         (g[2]-mu)*(g[2]-mu) + (g[3]-mu)*(g[3]-mu));
    float is = rsqrtf(var + 1e-5f);
    float mx = -3.0e38f;
    #pragma unroll
    for (int e = 0; e < 4; e++) { g[e] = (g[e] - mu) * is * gs[e] + bs[e]; mx = fmaxf(mx, g[e]); }
    float s = 0.f;
    #pragma unroll
    for (int e = 0; e < 4; e++) { g[e] = __expf(g[e] - mx); s += g[e]; }
    float inv = 1.f / s;
    float* gp = gates + ((size_t)bh * 100 + t) * 4;
    #pragma unroll
    for (int e = 0; e < 4; e++) gp[e] = g[e] * inv;
}

// ---------------- qkv projection GEMM ----------------
__global__ __launch_bounds__(256) void qkv_kernel(
    const void* __restrict__ x, const __bf16* __restrict__ Wts,
    const __bf16* __restrict__ Wtq, const int* __restrict__ modes,
    __bf16* __restrict__ q, __bf16* __restrict__ k, __bf16* __restrict__ v)
{
    const int m = modes[0];
    const int b = blockIdx.y;
    const int mt = blockIdx.x / 6;
    const int ntile = blockIdx.x % 6;
    const __bf16* Wt = (mt < 4) ? Wts : Wtq;
    const int tid = threadIdx.x;
    const int w = tid >> 6, l = tid & 63, lr = l & 15, lc = l >> 4;
    const int msub = w & 1, ngrp = w >> 1;
    const int rbase = (mt < 4) ? mt * 32 : 100 + (mt - 4) * 32;
    const int row = rbase + msub * 16 + lr;      // always < 164
    const size_t xrow = ((size_t)b * 164 + row) * 256;
    const int nb = ntile * 128 + ngrp * 64;
    f32x4 acc[4];
    #pragma unroll
    for (int nt = 0; nt < 4; nt++) acc[nt] = (f32x4){0.f, 0.f, 0.f, 0.f};
    #pragma unroll
    for (int kt = 0; kt < 8; kt++) {
        bf16x8 a = ldx8(x, xrow + kt * 32 + lc * 8, m);
        #pragma unroll
        for (int nt = 0; nt < 4; nt++) {
            bf16x8 bb = ldb8(Wt + (size_t)(nb + nt * 16 + lr) * 256 + kt * 32 + lc * 8);
            acc[nt] = __builtin_amdgcn_mfma_f32_16x16x32_bf16(a, bb, acc[nt], 0, 0, 0);
        }
    }
    const int i0 = rbase + msub * 16 + lc * 4;
    #pragma unroll
    for (int nt = 0; nt < 4; nt++) {
        int c = nb + nt * 16 + lr;
        __bf16* dst; int ch;
        if (c < 256)      { dst = q; ch = c; }
        else if (c < 512) { dst = k; ch = c - 256; }
        else              { dst = v; ch = c - 512; }
        int hh = ch >> 5, d = ch & 31;
        #pragma unroll
        for (int r = 0; r < 4; r++) {
            int i = i0 + r;
            if (mt >= 4 || i < 100)
                dst[(((size_t)b * 8 + hh) * 164 + i) * 32 + d] = (__bf16)acc[nt][r];
        }
    }
}

// ---------------- fused attention: S -> MoE -> softmax -> PV ----------------
// grid (2048, 3): x = b*8+h, y = row-tile (64 rows each; tile 2 = rows 128..163)
__global__ __launch_bounds__(256) void attn_kernel(
    const __bf16* __restrict__ qg, const __bf16* __restrict__ kg,
    const __bf16* __restrict__ vg, const float* __restrict__ gatesg,
    const int* __restrict__ maskg, const __bf16* __restrict__ w1t,
    const __bf16* __restrict__ w2t, const __bf16* __restrict__ wsm,
    __bf16* __restrict__ ohg)
{
    __shared__ __bf16 Ks[192][32];
    __shared__ __bf16 Vt[32][192];
    __shared__ __bf16 S[64][192];
    __shared__ __bf16 h1s[64][72];
    __shared__ float  gtile[64][4];
    __shared__ int    kmask[192];

    const __bf16* b1g = wsm + 140;
    const __bf16* b2g = wsm + 340;
    const int bh = blockIdx.x;
    const int rt = blockIdx.y;
    const int b = bh >> 3;
    const int tid = threadIdx.x;

    // ---- stage K (zero-pad rows >=164) ----
    const __bf16* kbase = kg + (size_t)bh * 164 * 32;
    for (int c = tid; c < 768; c += 256) {
        int row = c >> 2, part = c & 3;
        bf16x8 val = (row < 164) ? ldb8(kbase + row * 32 + part * 8) : zero8();
        *reinterpret_cast<bf16x8*>(&Ks[row][part * 8]) = val;
    }
    // ---- stage V transposed ----
    const __bf16* vbase = vg + (size_t)bh * 164 * 32;
    for (int c = tid; c < 656; c += 256) {
        int j = c >> 2, part = c & 3;
        bf16x8 val = ldb8(vbase + j * 32 + part * 8);
        #pragma unroll
        for (int u = 0; u < 8; u++) Vt[part * 8 + u][j] = val[u];
    }
    for (int c = tid; c < 896; c += 256) {
        int d = c & 31, j = 164 + (c >> 5);
        Vt[d][j] = (__bf16)0.f;
    }
    for (int j = tid; j < 192; j += 256)
        kmask[j] = (j < 164) ? maskg[b * 164 + j] : 1;
    {
        int il = tid >> 2, e = tid & 3, gi = rt * 64 + il;
        gtile[il][e] = (gi < 100) ? gatesg[((size_t)bh * 100 + gi) * 4 + e] : 0.f;
    }
    __syncthreads();

    const int w = tid >> 6, l = tid & 63;
    const int lr = l & 15, lc = l >> 4;
    const int m0 = w * 16;

    // ---- S = Q K^T * scale, key-mask to -1e30 ----
    int qrow = rt * 64 + m0 + lr; if (qrow > 163) qrow = 163;
    bf16x8 afq = ldb8(qg + ((size_t)bh * 164 + qrow) * 32 + lc * 8);
    #pragma unroll
    for (int nt = 0; nt < 12; nt++) {
        bf16x8 bf = ldb8(&Ks[nt * 16 + lr][lc * 8]);
        f32x4 acc = {0.f, 0.f, 0.f, 0.f};
        acc = __builtin_amdgcn_mfma_f32_16x16x32_bf16(afq, bf, acc, 0, 0, 0);
        int j = nt * 16 + lr;
        bool bad = (kmask[j] != 0);
        #pragma unroll
        for (int r = 0; r < 4; r++) {
            float v = acc[r] * 0.0625f;
            if (bad) v = -1e30f;
            S[m0 + lc * 4 + r][j] = (__bf16)v;
        }
    }

    // ---- MoE on rows < 100 (only row-tiles 0,1) ----
    if (rt < 2) {
        float moes[7][4];
        #pragma unroll
        for (int nt = 0; nt < 7; nt++)
            #pragma unroll
            for (int r = 0; r < 4; r++) moes[nt][r] = 0.f;
        for (int e = 0; e < 4; e++) {
            // h1 = relu(relu(S[:, :100]) @ w1[e] + b1[e])  (cols padded to 64)
            #pragma unroll
            for (int nt = 0; nt < 4; nt++) {
                f32x4 acc = {0.f, 0.f, 0.f, 0.f};
                #pragma unroll
                for (int kt = 0; kt < 4; kt++) {
                    int kb = kt * 32 + lc * 8;
                    bf16x8 a = ldb8(&S[m0 + lr][kb]);
                    #pragma unroll
                    for (int u = 0; u < 8; u++) {
                        float xv = (float)a[u];
                        xv = (kb + u >= 100 || xv < 0.f) ? 0.f : xv;
                        a[u] = (__bf16)xv;
                    }
                    bf16x8 bb = ldb8(w1t + (size_t)(e * 64 + nt * 16 + lr) * 128 + kb);
                    acc = __builtin_amdgcn_mfma_f32_16x16x32_bf16(a, bb, acc, 0, 0, 0);
                }
                int n = nt * 16 + lr;
                float bias = (n < 50) ? (float)b1g[e * 50 + n] : 0.f;
                #pragma unroll
                for (int r = 0; r < 4; r++) {
                    float v = acc[r] + bias;
                    if (v < 0.f) v = 0.f;
                    h1s[m0 + lc * 4 + r][n] = (__bf16)v;
                }
            }
            // eo = relu(h1 @ w2[e] + b2[e]); moes += eo * gate[i,e]
            #pragma unroll
            for (int nt = 0; nt < 7; nt++) {
                f32x4 acc = {0.f, 0.f, 0.f, 0.f};
                #pragma unroll
                for (int kt = 0; kt < 2; kt++) {
                    int kb = kt * 32 + lc * 8;
                    bf16x8 a = ldb8(&h1s[m0 + lr][kb]);
                    bf16x8 bb = ldb8(w2t + (size_t)(e * 112 + nt * 16 + lr) * 64 + kb);
                    acc = __builtin_amdgcn_mfma_f32_16x16x32_bf16(a, bb, acc, 0, 0, 0);
                }
                int n = nt * 16 + lr;
                float bias = (n < 100) ? (float)b2g[e * 100 + n] : 0.f;
                #pragma unroll
                for (int r = 0; r < 4; r++) {
                    float v = acc[r] + bias;
                    if (v < 0.f) v = 0.f;
                    moes[nt][r] += v * gtile[m0 + lc * 4 + r][e];
                }
            }
        }
        #pragma unroll
        for (int nt = 0; nt < 7; nt++) {
            int j = nt * 16 + lr;
            if (j < 100) {
                #pragma unroll
                for (int r = 0; r < 4; r++) {
                    int il = m0 + lc * 4 + r;
                    if (rt * 64 + il < 100) {
                        float v = (float)S[il][j] + moes[nt][r];
                        S[il][j] = (__bf16)v;
                    }
                }
            }
        }
    }
    __syncthreads();

    // ---- softmax per row (padding/masked cols are -1e30 -> weight 0) ----
    {
        int srow = m0 + lr;
        int c0 = lc * 48;
        float vals[48];
        float mx = -3.0e38f;
        #pragma unroll
        for (int c = 0; c < 48; c++) {
            float v = (float)S[srow][c0 + c];
            vals[c] = v;
            mx = fmaxf(mx, v);
        }
        mx = fmaxf(mx, __shfl_xor(mx, 16, 64));
        mx = fmaxf(mx, __shfl_xor(mx, 32, 64));
        float sum = 0.f;
        #pragma unroll
        for (int c = 0; c < 48; c++) {
            float ev = __expf(vals[c] - mx);
            vals[c] = ev;
            sum += ev;
        }
        sum += __shfl_xor(sum, 16, 64);
        sum += __shfl_xor(sum, 32, 64);
        float inv = (sum > 0.f) ? 1.f / sum : 0.f;
        #pragma unroll
        for (int c = 0; c < 48; c++)
            S[srow][c0 + c] = (__bf16)(vals[c] * inv);
    }
    __syncthreads();

    // ---- O = attn @ V ----
    #pragma unroll
    for (int nt = 0; nt < 2; nt++) {
        f32x4 acc = {0.f, 0.f, 0.f, 0.f};
        #pragma unroll
        for (int kt = 0; kt < 6; kt++) {
            bf16x8 a = ldb8(&S[m0 + lr][kt * 32 + lc * 8]);
            bf16x8 bb = ldb8(&Vt[nt * 16 + lr][kt * 32 + lc * 8]);
            acc = __builtin_amdgcn_mfma_f32_16x16x32_bf16(a, bb, acc, 0, 0, 0);
        }
        int d = nt * 16 + lr;
        #pragma unroll
        for (int r = 0; r < 4; r++) {
            int gi = rt * 64 + m0 + lc * 4 + r;
            if (gi < 164)
                ohg[((size_t)bh * 164 + gi) * 32 + d] = (__bf16)acc[r];
        }
    }
}

// ---------------- output projection (writes fp32!) ----------------
__global__ __launch_bounds__(256) void outproj_kernel(
    const __bf16* __restrict__ oh, const __bf16* __restrict__ wot,
    const __bf16* __restrict__ wsm, float* __restrict__ out)
{
    const __bf16* bout = wsm + 740;
    const int b = blockIdx.y;
    const int mt = blockIdx.x >> 1;
    const int ntile = blockIdx.x & 1;
    const int tid = threadIdx.x;
    const int w = tid >> 6, l = tid & 63, lr = l & 15, lc = l >> 4;
    int row = mt * 64 + w * 16 + lr; if (row > 163) row = 163;
    f32x4 acc[8];
    #pragma unroll
    for (int nt = 0; nt < 8; nt++) acc[nt] = (f32x4){0.f, 0.f, 0.f, 0.f};
    #pragma unroll
    for (int kt = 0; kt < 8; kt++) {   // k = kt*32 + lc*8 + u ; h = kt, d = lc*8+u
        bf16x8 a = ldb8(oh + (((size_t)b * 8 + kt) * 164 + row) * 32 + lc * 8);
        #pragma unroll
        for (int nt = 0; nt < 8; nt++) {
            bf16x8 bb = ldb8(wot + (size_t)(ntile * 128 + nt * 16 + lr) * 256 + kt * 32 + lc * 8);
            acc[nt] = __builtin_amdgcn_mfma_f32_16x16x32_bf16(a, bb, acc[nt], 0, 0, 0);
        }
    }
    #pragma unroll
    for (int nt = 0; nt < 8; nt++) {
        int n = ntile * 128 + nt * 16 + lr;
        float bias = (float)bout[n];
        #pragma unroll
        for (int r = 0; r < 4; r++) {
            int i = mt * 64 + w * 16 + lc * 4 + r;
            if (i < 164)
                out[((size_t)b * 164 + i) * 256 + n] = acc[nt][r] + bias;
        }
    }
}

extern "C" void kernel_launch(void* const* d_in, const int* in_sizes, int n_in,
                              void* d_out, int out_size, void* d_ws, size_t ws_size,
                              hipStream_t stream) {
    const void* x      = d_in[0];
    const void* mask   = d_in[1];
    const void* w_qk_s = d_in[2];
    const void* w_qk_q = d_in[3];
    const void* w_v    = d_in[4];
    const void* w_gate = d_in[5];
    const void* b_gate = d_in[6];
    const void* ln_g   = d_in[7];
    const void* ln_b   = d_in[8];
    const void* w1     = d_in[9];
    const void* b1     = d_in[10];
    const void* w2     = d_in[11];
    const void* b2     = d_in[12];
    const void* w_out  = d_in[13];
    const void* b_out  = d_in[14];
    float* out = (float*)d_out;

    char* ws = (char*)d_ws;
    size_t off = 0;
    auto nextp = [&](size_t bytes) {
        char* p = ws + off;
        off += (bytes + 255) & ~(size_t)255;
        return p;
    };
    const size_t QKV_ELEMS = (size_t)256 * 8 * 164 * 32;   // 10,747,904
    int*    modes  = (int*)nextp(64);
    int*    maskws = (int*)nextp((size_t)41984 * 4);
    __bf16* qws  = (__bf16*)nextp(QKV_ELEMS * 2);
    __bf16* kws  = (__bf16*)nextp(QKV_ELEMS * 2);
    __bf16* vws  = (__bf16*)nextp(QKV_ELEMS * 2);
    __bf16* ohws = (__bf16*)nextp(QKV_ELEMS * 2);
    float*  gws  = (float*)nextp((size_t)2048 * 100 * 4 * 4);
    __bf16* Wts  = (__bf16*)nextp(768 * 256 * 2);
    __bf16* Wtq  = (__bf16*)nextp(768 * 256 * 2);
    __bf16* w1t  = (__bf16*)nextp(4 * 64 * 128 * 2);
    __bf16* w2t  = (__bf16*)nextp(4 * 112 * 64 * 2);
    __bf16* wot  = (__bf16*)nextp(256 * 256 * 2);
    __bf16* wsm  = (__bf16*)nextp(996 * 2);

    detect_kernel<<<1, 256, 0, stream>>>(x, mask, modes, maskws);
    prep_kernel<<<1268, 256, 0, stream>>>(w_qk_s, w_qk_q, w_v, w1, w2, w_out,
                                          w_gate, b_gate, ln_g, ln_b, b1, b2,
                                          b_out, modes, Wts, Wtq, w1t, w2t, wot, wsm);
    gate_kernel<<<2048, 128, 0, stream>>>(x, wsm, modes, gws);
    qkv_kernel<<<dim3(36, 256), 256, 0, stream>>>(x, Wts, Wtq, modes, qws, kws, vws);
    attn_kernel<<<dim3(2048, 3), 256, 0, stream>>>(qws, kws, vws, gws, maskws,
                                                   w1t, w2t, wsm, ohws);
    outproj_kernel<<<dim3(6, 256), 256, 0, stream>>>(ohws, wot, wsm, out);
}

// Round 4
// 694.651 us; speedup vs baseline: 1.1111x; 1.1111x over previous
//
#include <hip/hip_runtime.h>

typedef __bf16 bf16x8 __attribute__((ext_vector_type(8)));
typedef float  f32x4  __attribute__((ext_vector_type(4)));

__device__ __forceinline__ bf16x8 ldb8(const __bf16* p) {
    return *reinterpret_cast<const bf16x8*>(p);
}
__device__ __forceinline__ bf16x8 zero8() {
    bf16x8 z;
    #pragma unroll
    for (int i = 0; i < 8; i++) z[i] = (__bf16)0.f;
    return z;
}
// mode m: 0 = storage is bf16, 1 = storage is fp32
__device__ __forceinline__ __bf16 ldw(const void* p, int i, int m) {
    return m ? (__bf16)((const float*)p)[i] : ((const __bf16*)p)[i];
}
__device__ __forceinline__ bf16x8 ldx8(const void* p, size_t ei, int m) {
    if (m) {
        const float* f = (const float*)p + ei;
        f32x4 a = *reinterpret_cast<const f32x4*>(f);
        f32x4 b = *reinterpret_cast<const f32x4*>(f + 4);
        bf16x8 r;
        #pragma unroll
        for (int u = 0; u < 4; u++) { r[u] = (__bf16)a[u]; r[4 + u] = (__bf16)b[u]; }
        return r;
    }
    return ldb8((const __bf16*)p + ei);
}

// ---------------- detect: input dtype + mask expand ----------------
__global__ __launch_bounds__(256) void detect_kernel(
    const void* x, const void* mask, int* modes, int* maskws)
{
    __shared__ int sbad, v32bad, v16bad;
    const int t = threadIdx.x;
    if (t == 0) { sbad = 0; v32bad = 0; v16bad = 0; }
    __syncthreads();
    const unsigned int* xw = (const unsigned int*)x;
    int bad = 0;
    for (int i = t; i < 2048; i += 256) {
        unsigned int w = xw[i];
        unsigned int el = (w >> 7) & 0xFF, eh = (w >> 23) & 0xFF;
        if (el >= 0x94 || el == 0xFF) bad++;
        if (eh >= 0x94 || eh == 0xFF) bad++;
    }
    if (bad) atomicAdd(&sbad, bad);
    const unsigned int* mw = (const unsigned int*)mask;
    int b32 = 0, b16 = 0;
    for (int i = t; i < 10496; i += 256) {
        unsigned int w = mw[i];
        if (!(w == 0u || w == 1u || w == 0x3F800000u)) b32++;
        unsigned int h0 = w & 0xFFFFu, h1 = w >> 16;
        if (!(h0 == 0u || h0 == 1u || h0 == 0x3F80u)) b16++;
        if (!(h1 == 0u || h1 == 1u || h1 == 0x3F80u)) b16++;
    }
    if (b32) atomicAdd(&v32bad, b32);
    if (b16) atomicAdd(&v16bad, b16);
    __syncthreads();
    const int mode_x = (sbad > 64) ? 1 : 0;
    const int mmode = (v32bad == 0) ? 0 : ((v16bad == 0) ? 2 : 1);
    if (t == 0) { modes[0] = mode_x; modes[1] = mmode; }
    for (int i = t; i < 41984; i += 256) {
        int val;
        if (mmode == 0)      val = (((const int*)mask)[i] != 0);
        else if (mmode == 2) val = (((const unsigned short*)mask)[i] != 0);
        else                 val = (((const unsigned char*)mask)[i] != 0);
        maskws[i] = val;
    }
}

// ---------------- prep: transpose/pad weights into ws (mode-aware) ----------------
// Wts/Wtq: (768 x 256)  rows 0..511 = w_qk^T (q|k), rows 512..767 = w_v^T
// w1t: (4 x 64 x 128)  w1[e]^T zero-padded (n<50, k<100)
// w2t: (4 x 112 x 64)  w2[e]^T zero-padded (n<100, k<50)
// wot: (256 x 256)     w_out^T
// wsm: [0:128)=w_gate [128:132)=b_gate [132:136)=ln_g [136:140)=ln_b
//      [140:340)=b1 [340:740)=b2 [740:996)=b_out
__global__ __launch_bounds__(256) void prep_kernel(
    const void* wqks, const void* wqkq, const void* wv, const void* w1,
    const void* w2, const void* wout, const void* wg, const void* bg,
    const void* lng, const void* lnb, const void* b1, const void* b2,
    const void* bout, const int* __restrict__ modes,
    __bf16* __restrict__ Wts, __bf16* __restrict__ Wtq,
    __bf16* __restrict__ w1t, __bf16* __restrict__ w2t,
    __bf16* __restrict__ wot, __bf16* __restrict__ wsm)
{
    const int m = modes[0];
    int i = blockIdx.x * 256 + threadIdx.x;
    if (i < 196608) {
        int n = i >> 8, k = i & 255;
        __bf16 vs, vq;
        if (n < 512) { vs = ldw(wqks, k * 512 + n, m); vq = ldw(wqkq, k * 512 + n, m); }
        else         { vs = ldw(wv, k * 256 + (n - 512), m); vq = vs; }
        Wts[i] = vs; Wtq[i] = vq;
        return;
    }
    i -= 196608;
    if (i < 32768) {
        int e = i >> 13, r = i & 8191, n = r >> 7, k = r & 127;
        w1t[i] = (n < 50 && k < 100) ? ldw(w1, (e * 100 + k) * 50 + n, m) : (__bf16)0.f;
        return;
    }
    i -= 32768;
    if (i < 28672) {
        int e = i / 7168, r = i % 7168, n = r >> 6, k = r & 63;
        w2t[i] = (n < 100 && k < 50) ? ldw(w2, (e * 50 + k) * 100 + n, m) : (__bf16)0.f;
        return;
    }
    i -= 28672;
    if (i < 65536) {
        int n = i >> 8, k = i & 255;
        wot[i] = ldw(wout, k * 256 + n, m);
        return;
    }
    i -= 65536;
    if (i < 996) {
        __bf16 v;
        if (i < 128)      v = ldw(wg, i, m);
        else if (i < 132) v = ldw(bg, i - 128, m);
        else if (i < 136) v = ldw(lng, i - 132, m);
        else if (i < 140) v = ldw(lnb, i - 136, m);
        else if (i < 340) v = ldw(b1, i - 140, m);
        else if (i < 740) v = ldw(b2, i - 340, m);
        else              v = ldw(bout, i - 740, m);
        wsm[i] = v;
    }
}

// ---------------- gates: g = gx@w_gate + b; LN; softmax ----------------
__global__ __launch_bounds__(128) void gate_kernel(
    const void* __restrict__ x, const __bf16* __restrict__ wsm,
    const int* __restrict__ modes, float* __restrict__ gates)
{
    __shared__ float wgs[128];
    __shared__ float bgs[4], gs[4], bs[4];
    const int bh = blockIdx.x, t = threadIdx.x;
    wgs[t] = (float)wsm[t];
    if (t < 4) { bgs[t] = (float)wsm[128 + t]; gs[t] = (float)wsm[132 + t]; bs[t] = (float)wsm[136 + t]; }
    __syncthreads();
    if (t >= 100) return;
    const int m = modes[0];
    const int b = bh >> 3, h = bh & 7;
    const size_t base = (size_t)b * 41984 + h * 5248 + t * 32;
    float g[4] = {bgs[0], bgs[1], bgs[2], bgs[3]};
    #pragma unroll
    for (int p = 0; p < 4; p++) {
        bf16x8 xv = ldx8(x, base + p * 8, m);
        #pragma unroll
        for (int u = 0; u < 8; u++) {
            float f = (float)xv[u];
            #pragma unroll
            for (int e = 0; e < 4; e++) g[e] += f * wgs[(p * 8 + u) * 4 + e];
        }
    }
    float mu = 0.25f * (g[0] + g[1] + g[2] + g[3]);
    float var = 0.25f * ((g[0]-mu)*(g[0]-mu) + (g[1]-mu)*(g[1]-mu) +
                         (g[2]-mu)*(g[2]-mu) + (g[3]-mu)*(g[3]-mu));
    float is = rsqrtf(var + 1e-5f);
    float mx = -3.0e38f;
    #pragma unroll
    for (int e = 0; e < 4; e++) { g[e] = (g[e] - mu) * is * gs[e] + bs[e]; mx = fmaxf(mx, g[e]); }
    float s = 0.f;
    #pragma unroll
    for (int e = 0; e < 4; e++) { g[e] = __expf(g[e] - mx); s += g[e]; }
    float inv = 1.f / s;
    float* gp = gates + ((size_t)bh * 100 + t) * 4;
    #pragma unroll
    for (int e = 0; e < 4; e++) gp[e] = g[e] * inv;
}

// ---------------- qkv projection GEMM v2 ----------------
// grid (6, B): mt = blockIdx.x. Block = 32 rows x 768 cols; x staged to LDS once.
// wave w: cols w*192..+191 (12 nt tiles), rows 0..31 (2 m-sub tiles).
__global__ __launch_bounds__(256, 2) void qkv_kernel(
    const void* __restrict__ x, const __bf16* __restrict__ Wts,
    const __bf16* __restrict__ Wtq, const int* __restrict__ modes,
    __bf16* __restrict__ q, __bf16* __restrict__ k, __bf16* __restrict__ v)
{
    __shared__ __bf16 xs[32][264];   // stride 264: +4 banks/row, 16B-aligned
    const int m = modes[0];
    const int b = blockIdx.y;
    const int mt = blockIdx.x;
    const __bf16* Wt = (mt < 4) ? Wts : Wtq;
    const int rbase = (mt < 4) ? mt * 32 : 100 + (mt - 4) * 32;
    const int tid = threadIdx.x;

    for (int c = tid; c < 1024; c += 256) {
        int row = c >> 5, part = c & 31;
        bf16x8 val = ldx8(x, ((size_t)b * 164 + rbase + row) * 256 + part * 8, m);
        *reinterpret_cast<bf16x8*>(&xs[row][part * 8]) = val;
    }
    __syncthreads();

    const int w = tid >> 6, l = tid & 63, lr = l & 15, lc = l >> 4;
    f32x4 acc[2][12];
    #pragma unroll
    for (int ms = 0; ms < 2; ms++)
        #pragma unroll
        for (int nt = 0; nt < 12; nt++) acc[ms][nt] = (f32x4){0.f, 0.f, 0.f, 0.f};

    #pragma unroll
    for (int kt = 0; kt < 8; kt++) {
        bf16x8 a0 = ldb8(&xs[lr][kt * 32 + lc * 8]);
        bf16x8 a1 = ldb8(&xs[16 + lr][kt * 32 + lc * 8]);
        #pragma unroll
        for (int nt = 0; nt < 12; nt++) {
            bf16x8 bb = ldb8(Wt + (size_t)(w * 192 + nt * 16 + lr) * 256 + kt * 32 + lc * 8);
            acc[0][nt] = __builtin_amdgcn_mfma_f32_16x16x32_bf16(a0, bb, acc[0][nt], 0, 0, 0);
            acc[1][nt] = __builtin_amdgcn_mfma_f32_16x16x32_bf16(a1, bb, acc[1][nt], 0, 0, 0);
        }
    }
    #pragma unroll
    for (int ms = 0; ms < 2; ms++) {
        #pragma unroll
        for (int nt = 0; nt < 12; nt++) {
            int c = w * 192 + nt * 16 + lr;
            __bf16* dst; int ch;
            if (c < 256)      { dst = q; ch = c; }
            else if (c < 512) { dst = k; ch = c - 256; }
            else              { dst = v; ch = c - 512; }
            int hh = ch >> 5, d = ch & 31;
            #pragma unroll
            for (int r = 0; r < 4; r++) {
                int i = rbase + ms * 16 + lc * 4 + r;
                if (mt >= 4 || i < 100)
                    dst[(((size_t)b * 8 + hh) * 164 + i) * 32 + d] = (__bf16)acc[ms][nt][r];
            }
        }
    }
}

// ---------------- fused attention v2: regs-resident scores ----------------
// grid (2048, 3). LDS ~52KB -> 3 blocks/CU. Ks/Vt union; padded strides.
__global__ __launch_bounds__(256, 3) void attn_kernel(
    const __bf16* __restrict__ qg, const __bf16* __restrict__ kg,
    const __bf16* __restrict__ vg, const float* __restrict__ gatesg,
    const int* __restrict__ maskg, const __bf16* __restrict__ w1t,
    const __bf16* __restrict__ w2t, const __bf16* __restrict__ wsm,
    __bf16* __restrict__ ohg)
{
    __shared__ __bf16 KV[7680];        // Ks[192][40] (QK) then Vt[32][200] (PV)
    __shared__ __bf16 S[64][200];      // relu-scores (MoE), then probs (PV)
    __shared__ __bf16 h1s[64][72];
    __shared__ float  gtile[64][4];
    __shared__ int    kmask[192];

    const __bf16* b1g = wsm + 140;
    const __bf16* b2g = wsm + 340;
    const int bh = blockIdx.x, rt = blockIdx.y, b = bh >> 3, tid = threadIdx.x;

    // ---- stage K (padded stride 40), kmask, gates ----
    const __bf16* kbase = kg + (size_t)bh * 164 * 32;
    for (int c = tid; c < 768; c += 256) {
        int row = c >> 2, part = c & 3;
        bf16x8 val = (row < 164) ? ldb8(kbase + row * 32 + part * 8) : zero8();
        *reinterpret_cast<bf16x8*>(&KV[row * 40 + part * 8]) = val;
    }
    for (int j = tid; j < 192; j += 256)
        kmask[j] = (j < 164) ? maskg[b * 164 + j] : 1;
    {
        int il = tid >> 2, e = tid & 3, gi = rt * 64 + il;
        gtile[il][e] = (gi < 100) ? gatesg[((size_t)bh * 100 + gi) * 4 + e] : 0.f;
    }
    __syncthreads();

    const int w = tid >> 6, l = tid & 63, lr = l & 15, lc = l >> 4;
    const int m0 = w * 16;

    // ---- QK^T -> raw scores in registers (C layout: row=m0+lc*4+r, col=nt*16+lr)
    int qrow = rt * 64 + m0 + lr; if (qrow > 163) qrow = 163;
    bf16x8 afq = ldb8(qg + ((size_t)bh * 164 + qrow) * 32 + lc * 8);
    f32x4 raw[12];
    #pragma unroll
    for (int nt = 0; nt < 12; nt++) {
        bf16x8 bf = ldb8(&KV[(nt * 16 + lr) * 40 + lc * 8]);
        f32x4 acc = {0.f, 0.f, 0.f, 0.f};
        acc = __builtin_amdgcn_mfma_f32_16x16x32_bf16(afq, bf, acc, 0, 0, 0);
        int j = nt * 16 + lr;
        bool bad = (kmask[j] != 0);
        #pragma unroll
        for (int r = 0; r < 4; r++)
            raw[nt][r] = bad ? -1e30f : acc[r] * 0.0625f;
    }
    // write relu'd scores (cols 0..127, zero for j>=100) for MoE A operand
    #pragma unroll
    for (int nt = 0; nt < 8; nt++) {
        int j = nt * 16 + lr;
        #pragma unroll
        for (int r = 0; r < 4; r++) {
            float v = raw[nt][r];
            v = (j >= 100 || v < 0.f) ? 0.f : v;
            S[m0 + lc * 4 + r][j] = (__bf16)v;
        }
    }
    __syncthreads();   // all waves done reading Ks -> safe to overwrite with Vt

    // ---- stage V transposed into KV region (stride 200); overlaps MoE ----
    const __bf16* vbase = vg + (size_t)bh * 164 * 32;
    for (int c = tid; c < 656; c += 256) {
        int j = c >> 2, part = c & 3;
        bf16x8 val = ldb8(vbase + j * 32 + part * 8);
        #pragma unroll
        for (int u = 0; u < 8; u++) KV[(part * 8 + u) * 200 + j] = val[u];
    }
    for (int c = tid; c < 896; c += 256) {
        int d = c & 31, j = 164 + (c >> 5);
        KV[d * 200 + j] = (__bf16)0.f;
    }

    // ---- MoE (rows < 128 tiles only) ----
    float moes[7][4];
    #pragma unroll
    for (int nt = 0; nt < 7; nt++)
        #pragma unroll
        for (int r = 0; r < 4; r++) moes[nt][r] = 0.f;
    if (rt < 2) {
        bf16x8 sa[4];
        #pragma unroll
        for (int kt = 0; kt < 4; kt++) sa[kt] = ldb8(&S[m0 + lr][kt * 32 + lc * 8]);
        for (int e = 0; e < 4; e++) {
            #pragma unroll
            for (int nt = 0; nt < 4; nt++) {
                f32x4 acc = {0.f, 0.f, 0.f, 0.f};
                #pragma unroll
                for (int kt = 0; kt < 4; kt++) {
                    bf16x8 bb = ldb8(w1t + (size_t)(e * 64 + nt * 16 + lr) * 128 + kt * 32 + lc * 8);
                    acc = __builtin_amdgcn_mfma_f32_16x16x32_bf16(sa[kt], bb, acc, 0, 0, 0);
                }
                int n = nt * 16 + lr;
                float bias = (n < 50) ? (float)b1g[e * 50 + n] : 0.f;
                #pragma unroll
                for (int r = 0; r < 4; r++) {
                    float v = acc[r] + bias;
                    if (v < 0.f) v = 0.f;
                    h1s[m0 + lc * 4 + r][n] = (__bf16)v;
                }
            }
            bf16x8 ha0 = ldb8(&h1s[m0 + lr][lc * 8]);
            bf16x8 ha1 = ldb8(&h1s[m0 + lr][32 + lc * 8]);
            float gt[4];
            #pragma unroll
            for (int r = 0; r < 4; r++) gt[r] = gtile[m0 + lc * 4 + r][e];
            #pragma unroll
            for (int nt = 0; nt < 7; nt++) {
                f32x4 acc = {0.f, 0.f, 0.f, 0.f};
                bf16x8 bb0 = ldb8(w2t + (size_t)(e * 112 + nt * 16 + lr) * 64 + lc * 8);
                bf16x8 bb1 = ldb8(w2t + (size_t)(e * 112 + nt * 16 + lr) * 64 + 32 + lc * 8);
                acc = __builtin_amdgcn_mfma_f32_16x16x32_bf16(ha0, bb0, acc, 0, 0, 0);
                acc = __builtin_amdgcn_mfma_f32_16x16x32_bf16(ha1, bb1, acc, 0, 0, 0);
                int n = nt * 16 + lr;
                float bias = (n < 100) ? (float)b2g[e * 100 + n] : 0.f;
                #pragma unroll
                for (int r = 0; r < 4; r++) {
                    float v = acc[r] + bias;
                    if (v < 0.f) v = 0.f;
                    moes[nt][r] += v * gt[r];
                }
            }
        }
    }

    // ---- add moes; in-register softmax (row = m0+lc*4+r spread over lr lanes) ----
    #pragma unroll
    for (int nt = 0; nt < 7; nt++)
        #pragma unroll
        for (int r = 0; r < 4; r++) raw[nt][r] += moes[nt][r];

    float mx[4], sum[4];
    #pragma unroll
    for (int r = 0; r < 4; r++) {
        float m2 = -3.0e38f;
        #pragma unroll
        for (int nt = 0; nt < 12; nt++) m2 = fmaxf(m2, raw[nt][r]);
        m2 = fmaxf(m2, __shfl_xor(m2, 1, 64));
        m2 = fmaxf(m2, __shfl_xor(m2, 2, 64));
        m2 = fmaxf(m2, __shfl_xor(m2, 4, 64));
        m2 = fmaxf(m2, __shfl_xor(m2, 8, 64));
        mx[r] = m2;
        float s2 = 0.f;
        #pragma unroll
        for (int nt = 0; nt < 12; nt++) {
            float ev = __expf(raw[nt][r] - m2);
            raw[nt][r] = ev;
            s2 += ev;
        }
        s2 += __shfl_xor(s2, 1, 64);
        s2 += __shfl_xor(s2, 2, 64);
        s2 += __shfl_xor(s2, 4, 64);
        s2 += __shfl_xor(s2, 8, 64);
        sum[r] = s2;
    }
    #pragma unroll
    for (int r = 0; r < 4; r++) {
        float inv = (sum[r] > 0.f) ? 1.f / sum[r] : 0.f;
        #pragma unroll
        for (int nt = 0; nt < 12; nt++)
            S[m0 + lc * 4 + r][nt * 16 + lr] = (__bf16)(raw[nt][r] * inv);
    }
    __syncthreads();   // Vt staged by all threads

    // ---- O = attn @ V ----
    bf16x8 pa[6];
    #pragma unroll
    for (int kt = 0; kt < 6; kt++) pa[kt] = ldb8(&S[m0 + lr][kt * 32 + lc * 8]);
    #pragma unroll
    for (int nt = 0; nt < 2; nt++) {
        f32x4 acc = {0.f, 0.f, 0.f, 0.f};
        #pragma unroll
        for (int kt = 0; kt < 6; kt++) {
            bf16x8 bb = ldb8(&KV[(nt * 16 + lr) * 200 + kt * 32 + lc * 8]);
            acc = __builtin_amdgcn_mfma_f32_16x16x32_bf16(pa[kt], bb, acc, 0, 0, 0);
        }
        int d = nt * 16 + lr;
        #pragma unroll
        for (int r = 0; r < 4; r++) {
            int gi = rt * 64 + m0 + lc * 4 + r;
            if (gi < 164)
                ohg[((size_t)bh * 164 + gi) * 32 + d] = (__bf16)acc[r];
        }
    }
}

// ---------------- output projection (writes fp32) ----------------
__global__ __launch_bounds__(256) void outproj_kernel(
    const __bf16* __restrict__ oh, const __bf16* __restrict__ wot,
    const __bf16* __restrict__ wsm, float* __restrict__ out)
{
    const __bf16* bout = wsm + 740;
    const int b = blockIdx.y;
    const int mt = blockIdx.x >> 1;
    const int ntile = blockIdx.x & 1;
    const int tid = threadIdx.x;
    const int w = tid >> 6, l = tid & 63, lr = l & 15, lc = l >> 4;
    int row = mt * 64 + w * 16 + lr; if (row > 163) row = 163;
    f32x4 acc[8];
    #pragma unroll
    for (int nt = 0; nt < 8; nt++) acc[nt] = (f32x4){0.f, 0.f, 0.f, 0.f};
    #pragma unroll
    for (int kt = 0; kt < 8; kt++) {
        bf16x8 a = ldb8(oh + (((size_t)b * 8 + kt) * 164 + row) * 32 + lc * 8);
        #pragma unroll
        for (int nt = 0; nt < 8; nt++) {
            bf16x8 bb = ldb8(wot + (size_t)(ntile * 128 + nt * 16 + lr) * 256 + kt * 32 + lc * 8);
            acc[nt] = __builtin_amdgcn_mfma_f32_16x16x32_bf16(a, bb, acc[nt], 0, 0, 0);
        }
    }
    #pragma unroll
    for (int nt = 0; nt < 8; nt++) {
        int n = ntile * 128 + nt * 16 + lr;
        float bias = (float)bout[n];
        #pragma unroll
        for (int r = 0; r < 4; r++) {
            int i = mt * 64 + w * 16 + lc * 4 + r;
            if (i < 164)
                out[((size_t)b * 164 + i) * 256 + n] = acc[nt][r] + bias;
        }
    }
}

extern "C" void kernel_launch(void* const* d_in, const int* in_sizes, int n_in,
                              void* d_out, int out_size, void* d_ws, size_t ws_size,
                              hipStream_t stream) {
    const void* x      = d_in[0];
    const void* mask   = d_in[1];
    const void* w_qk_s = d_in[2];
    const void* w_qk_q = d_in[3];
    const void* w_v    = d_in[4];
    const void* w_gate = d_in[5];
    const void* b_gate = d_in[6];
    const void* ln_g   = d_in[7];
    const void* ln_b   = d_in[8];
    const void* w1     = d_in[9];
    const void* b1     = d_in[10];
    const void* w2     = d_in[11];
    const void* b2     = d_in[12];
    const void* w_out  = d_in[13];
    const void* b_out  = d_in[14];
    float* out = (float*)d_out;

    char* ws = (char*)d_ws;
    size_t off = 0;
    auto nextp = [&](size_t bytes) {
        char* p = ws + off;
        off += (bytes + 255) & ~(size_t)255;
        return p;
    };
    const size_t QKV_ELEMS = (size_t)256 * 8 * 164 * 32;   // 10,747,904
    int*    modes  = (int*)nextp(64);
    int*    maskws = (int*)nextp((size_t)41984 * 4);
    __bf16* qws  = (__bf16*)nextp(QKV_ELEMS * 2);
    __bf16* kws  = (__bf16*)nextp(QKV_ELEMS * 2);
    __bf16* vws  = (__bf16*)nextp(QKV_ELEMS * 2);
    __bf16* ohws = (__bf16*)nextp(QKV_ELEMS * 2);
    float*  gws  = (float*)nextp((size_t)2048 * 100 * 4 * 4);
    __bf16* Wts  = (__bf16*)nextp(768 * 256 * 2);
    __bf16* Wtq  = (__bf16*)nextp(768 * 256 * 2);
    __bf16* w1t  = (__bf16*)nextp(4 * 64 * 128 * 2);
    __bf16* w2t  = (__bf16*)nextp(4 * 112 * 64 * 2);
    __bf16* wot  = (__bf16*)nextp(256 * 256 * 2);
    __bf16* wsm  = (__bf16*)nextp(996 * 2);

    detect_kernel<<<1, 256, 0, stream>>>(x, mask, modes, maskws);
    prep_kernel<<<1268, 256, 0, stream>>>(w_qk_s, w_qk_q, w_v, w1, w2, w_out,
                                          w_gate, b_gate, ln_g, ln_b, b1, b2,
                                          b_out, modes, Wts, Wtq, w1t, w2t, wot, wsm);
    gate_kernel<<<2048, 128, 0, stream>>>(x, wsm, modes, gws);
    qkv_kernel<<<dim3(6, 256), 256, 0, stream>>>(x, Wts, Wtq, modes, qws, kws, vws);
    attn_kernel<<<dim3(2048, 3), 256, 0, stream>>>(qws, kws, vws, gws, maskws,
                                                   w1t, w2t, wsm, ohws);
    outproj_kernel<<<dim3(6, 256), 256, 0, stream>>>(ohws, wot, wsm, out);
}

// Round 5
// 601.598 us; speedup vs baseline: 1.2830x; 1.1547x over previous
//
#include <hip/hip_runtime.h>

typedef __bf16 bf16x8 __attribute__((ext_vector_type(8)));
typedef float  f32x4  __attribute__((ext_vector_type(4)));

__device__ __forceinline__ bf16x8 ldb8(const __bf16* p) {
    return *reinterpret_cast<const bf16x8*>(p);
}
__device__ __forceinline__ bf16x8 zero8() {
    bf16x8 z;
    #pragma unroll
    for (int i = 0; i < 8; i++) z[i] = (__bf16)0.f;
    return z;
}
// mode m: 0 = storage is bf16, 1 = storage is fp32
__device__ __forceinline__ __bf16 ldw(const void* p, int i, int m) {
    return m ? (__bf16)((const float*)p)[i] : ((const __bf16*)p)[i];
}
__device__ __forceinline__ bf16x8 ldx8(const void* p, size_t ei, int m) {
    if (m) {
        const float* f = (const float*)p + ei;
        f32x4 a = *reinterpret_cast<const f32x4*>(f);
        f32x4 b = *reinterpret_cast<const f32x4*>(f + 4);
        bf16x8 r;
        #pragma unroll
        for (int u = 0; u < 4; u++) { r[u] = (__bf16)a[u]; r[4 + u] = (__bf16)b[u]; }
        return r;
    }
    return ldb8((const __bf16*)p + ei);
}

// ---------------- detect: input dtype + mask expand ----------------
__global__ __launch_bounds__(256) void detect_kernel(
    const void* x, const void* mask, int* modes, int* maskws)
{
    __shared__ int sbad, v32bad, v16bad;
    const int t = threadIdx.x;
    if (t == 0) { sbad = 0; v32bad = 0; v16bad = 0; }
    __syncthreads();
    const unsigned int* xw = (const unsigned int*)x;
    int bad = 0;
    for (int i = t; i < 2048; i += 256) {
        unsigned int w = xw[i];
        unsigned int el = (w >> 7) & 0xFF, eh = (w >> 23) & 0xFF;
        if (el >= 0x94 || el == 0xFF) bad++;
        if (eh >= 0x94 || eh == 0xFF) bad++;
    }
    if (bad) atomicAdd(&sbad, bad);
    const unsigned int* mw = (const unsigned int*)mask;
    int b32 = 0, b16 = 0;
    for (int i = t; i < 10496; i += 256) {
        unsigned int w = mw[i];
        if (!(w == 0u || w == 1u || w == 0x3F800000u)) b32++;
        unsigned int h0 = w & 0xFFFFu, h1 = w >> 16;
        if (!(h0 == 0u || h0 == 1u || h0 == 0x3F80u)) b16++;
        if (!(h1 == 0u || h1 == 1u || h1 == 0x3F80u)) b16++;
    }
    if (b32) atomicAdd(&v32bad, b32);
    if (b16) atomicAdd(&v16bad, b16);
    __syncthreads();
    const int mode_x = (sbad > 64) ? 1 : 0;
    const int mmode = (v32bad == 0) ? 0 : ((v16bad == 0) ? 2 : 1);
    if (t == 0) { modes[0] = mode_x; modes[1] = mmode; }
    for (int i = t; i < 41984; i += 256) {
        int val;
        if (mmode == 0)      val = (((const int*)mask)[i] != 0);
        else if (mmode == 2) val = (((const unsigned short*)mask)[i] != 0);
        else                 val = (((const unsigned char*)mask)[i] != 0);
        maskws[i] = val;
    }
}

// ---------------- prep: transpose/pad weights into ws (mode-aware) ----------------
// Wts/Wtq: (768 x 256)  rows 0..511 = w_qk^T (q|k), rows 512..767 = w_v^T
// w1t: (4 x 64 x 128)  w1[e]^T zero-padded (n<50, k<100)
// w2t: (4 x 112 x 64)  w2[e]^T zero-padded (n<100, k<50)
// wot: (256 x 256)     w_out^T
// wsm: [0:128)=w_gate [128:132)=b_gate [132:136)=ln_g [136:140)=ln_b
//      [140:340)=b1 [340:740)=b2 [740:996)=b_out
__global__ __launch_bounds__(256) void prep_kernel(
    const void* wqks, const void* wqkq, const void* wv, const void* w1,
    const void* w2, const void* wout, const void* wg, const void* bg,
    const void* lng, const void* lnb, const void* b1, const void* b2,
    const void* bout, const int* __restrict__ modes,
    __bf16* __restrict__ Wts, __bf16* __restrict__ Wtq,
    __bf16* __restrict__ w1t, __bf16* __restrict__ w2t,
    __bf16* __restrict__ wot, __bf16* __restrict__ wsm)
{
    const int m = modes[0];
    int i = blockIdx.x * 256 + threadIdx.x;
    if (i < 196608) {
        int n = i >> 8, k = i & 255;
        __bf16 vs, vq;
        if (n < 512) { vs = ldw(wqks, k * 512 + n, m); vq = ldw(wqkq, k * 512 + n, m); }
        else         { vs = ldw(wv, k * 256 + (n - 512), m); vq = vs; }
        Wts[i] = vs; Wtq[i] = vq;
        return;
    }
    i -= 196608;
    if (i < 32768) {
        int e = i >> 13, r = i & 8191, n = r >> 7, k = r & 127;
        w1t[i] = (n < 50 && k < 100) ? ldw(w1, (e * 100 + k) * 50 + n, m) : (__bf16)0.f;
        return;
    }
    i -= 32768;
    if (i < 28672) {
        int e = i / 7168, r = i % 7168, n = r >> 6, k = r & 63;
        w2t[i] = (n < 100 && k < 50) ? ldw(w2, (e * 50 + k) * 100 + n, m) : (__bf16)0.f;
        return;
    }
    i -= 28672;
    if (i < 65536) {
        int n = i >> 8, k = i & 255;
        wot[i] = ldw(wout, k * 256 + n, m);
        return;
    }
    i -= 65536;
    if (i < 996) {
        __bf16 v;
        if (i < 128)      v = ldw(wg, i, m);
        else if (i < 132) v = ldw(bg, i - 128, m);
        else if (i < 136) v = ldw(lng, i - 132, m);
        else if (i < 140) v = ldw(lnb, i - 136, m);
        else if (i < 340) v = ldw(b1, i - 140, m);
        else if (i < 740) v = ldw(b2, i - 340, m);
        else              v = ldw(bout, i - 740, m);
        wsm[i] = v;
    }
}

// ---------------- gates: g = gx@w_gate + b; LN; softmax ----------------
__global__ __launch_bounds__(128) void gate_kernel(
    const void* __restrict__ x, const __bf16* __restrict__ wsm,
    const int* __restrict__ modes, float* __restrict__ gates)
{
    __shared__ float wgs[128];
    __shared__ float bgs[4], gs[4], bs[4];
    const int bh = blockIdx.x, t = threadIdx.x;
    wgs[t] = (float)wsm[t];
    if (t < 4) { bgs[t] = (float)wsm[128 + t]; gs[t] = (float)wsm[132 + t]; bs[t] = (float)wsm[136 + t]; }
    __syncthreads();
    if (t >= 100) return;
    const int m = modes[0];
    const int b = bh >> 3, h = bh & 7;
    const size_t base = (size_t)b * 41984 + h * 5248 + t * 32;
    float g[4] = {bgs[0], bgs[1], bgs[2], bgs[3]};
    #pragma unroll
    for (int p = 0; p < 4; p++) {
        bf16x8 xv = ldx8(x, base + p * 8, m);
        #pragma unroll
        for (int u = 0; u < 8; u++) {
            float f = (float)xv[u];
            #pragma unroll
            for (int e = 0; e < 4; e++) g[e] += f * wgs[(p * 8 + u) * 4 + e];
        }
    }
    float mu = 0.25f * (g[0] + g[1] + g[2] + g[3]);
    float var = 0.25f * ((g[0]-mu)*(g[0]-mu) + (g[1]-mu)*(g[1]-mu) +
                         (g[2]-mu)*(g[2]-mu) + (g[3]-mu)*(g[3]-mu));
    float is = rsqrtf(var + 1e-5f);
    float mx = -3.0e38f;
    #pragma unroll
    for (int e = 0; e < 4; e++) { g[e] = (g[e] - mu) * is * gs[e] + bs[e]; mx = fmaxf(mx, g[e]); }
    float s = 0.f;
    #pragma unroll
    for (int e = 0; e < 4; e++) { g[e] = __expf(g[e] - mx); s += g[e]; }
    float inv = 1.f / s;
    float* gp = gates + ((size_t)bh * 100 + t) * 4;
    #pragma unroll
    for (int e = 0; e < 4; e++) gp[e] = g[e] * inv;
}

// ---------------- qkv projection GEMM v2 ----------------
__global__ __launch_bounds__(256, 2) void qkv_kernel(
    const void* __restrict__ x, const __bf16* __restrict__ Wts,
    const __bf16* __restrict__ Wtq, const int* __restrict__ modes,
    __bf16* __restrict__ q, __bf16* __restrict__ k, __bf16* __restrict__ v)
{
    __shared__ __bf16 xs[32][264];
    const int m = modes[0];
    const int b = blockIdx.y;
    const int mt = blockIdx.x;
    const __bf16* Wt = (mt < 4) ? Wts : Wtq;
    const int rbase = (mt < 4) ? mt * 32 : 100 + (mt - 4) * 32;
    const int tid = threadIdx.x;

    for (int c = tid; c < 1024; c += 256) {
        int row = c >> 5, part = c & 31;
        bf16x8 val = ldx8(x, ((size_t)b * 164 + rbase + row) * 256 + part * 8, m);
        *reinterpret_cast<bf16x8*>(&xs[row][part * 8]) = val;
    }
    __syncthreads();

    const int w = tid >> 6, l = tid & 63, lr = l & 15, lc = l >> 4;
    f32x4 acc[2][12];
    #pragma unroll
    for (int ms = 0; ms < 2; ms++)
        #pragma unroll
        for (int nt = 0; nt < 12; nt++) acc[ms][nt] = (f32x4){0.f, 0.f, 0.f, 0.f};

    #pragma unroll
    for (int kt = 0; kt < 8; kt++) {
        bf16x8 a0 = ldb8(&xs[lr][kt * 32 + lc * 8]);
        bf16x8 a1 = ldb8(&xs[16 + lr][kt * 32 + lc * 8]);
        #pragma unroll
        for (int nt = 0; nt < 12; nt++) {
            bf16x8 bb = ldb8(Wt + (size_t)(w * 192 + nt * 16 + lr) * 256 + kt * 32 + lc * 8);
            acc[0][nt] = __builtin_amdgcn_mfma_f32_16x16x32_bf16(a0, bb, acc[0][nt], 0, 0, 0);
            acc[1][nt] = __builtin_amdgcn_mfma_f32_16x16x32_bf16(a1, bb, acc[1][nt], 0, 0, 0);
        }
    }
    #pragma unroll
    for (int ms = 0; ms < 2; ms++) {
        #pragma unroll
        for (int nt = 0; nt < 12; nt++) {
            int c = w * 192 + nt * 16 + lr;
            __bf16* dst; int ch;
            if (c < 256)      { dst = q; ch = c; }
            else if (c < 512) { dst = k; ch = c - 256; }
            else              { dst = v; ch = c - 512; }
            int hh = ch >> 5, d = ch & 31;
            #pragma unroll
            for (int r = 0; r < 4; r++) {
                int i = rbase + ms * 16 + lc * 4 + r;
                if (mt >= 4 || i < 100)
                    dst[(((size_t)b * 8 + hh) * 164 + i) * 32 + d] = (__bf16)acc[ms][nt][r];
            }
        }
    }
}

// ---------------- fused attention v3: regs-resident scores, low pressure ----------------
// grid (2048, 3). LDS ~52KB -> 3 blocks/CU. MoE accumulates directly into raw.
__global__ __launch_bounds__(256, 3) void attn_kernel(
    const __bf16* __restrict__ qg, const __bf16* __restrict__ kg,
    const __bf16* __restrict__ vg, const float* __restrict__ gatesg,
    const int* __restrict__ maskg, const __bf16* __restrict__ w1t,
    const __bf16* __restrict__ w2t, const __bf16* __restrict__ wsm,
    __bf16* __restrict__ ohg)
{
    __shared__ __bf16 KV[7680];        // Ks[192][40] (QK) then Vt[32][200] (PV)
    __shared__ __bf16 S[64][200];      // relu-scores (MoE), then probs (PV)
    __shared__ __bf16 h1s[64][72];
    __shared__ float  gtile[64][4];
    __shared__ int    kmask[192];

    const __bf16* b1g = wsm + 140;
    const __bf16* b2g = wsm + 340;
    const int bh = blockIdx.x, rt = blockIdx.y, b = bh >> 3, tid = threadIdx.x;

    // ---- stage K (padded stride 40), kmask, gates ----
    const __bf16* kbase = kg + (size_t)bh * 164 * 32;
    for (int c = tid; c < 768; c += 256) {
        int row = c >> 2, part = c & 3;
        bf16x8 val = (row < 164) ? ldb8(kbase + row * 32 + part * 8) : zero8();
        *reinterpret_cast<bf16x8*>(&KV[row * 40 + part * 8]) = val;
    }
    for (int j = tid; j < 192; j += 256)
        kmask[j] = (j < 164) ? maskg[b * 164 + j] : 1;
    {
        int il = tid >> 2, e = tid & 3, gi = rt * 64 + il;
        gtile[il][e] = (gi < 100) ? gatesg[((size_t)bh * 100 + gi) * 4 + e] : 0.f;
    }
    __syncthreads();

    const int w = tid >> 6, l = tid & 63, lr = l & 15, lc = l >> 4;
    const int m0 = w * 16;

    // ---- QK^T -> raw scores in registers (C layout: row=m0+lc*4+r, col=nt*16+lr)
    int qrow = rt * 64 + m0 + lr; if (qrow > 163) qrow = 163;
    bf16x8 afq = ldb8(qg + ((size_t)bh * 164 + qrow) * 32 + lc * 8);
    f32x4 raw[12];
    #pragma unroll
    for (int nt = 0; nt < 12; nt++) {
        bf16x8 bf = ldb8(&KV[(nt * 16 + lr) * 40 + lc * 8]);
        f32x4 acc = {0.f, 0.f, 0.f, 0.f};
        acc = __builtin_amdgcn_mfma_f32_16x16x32_bf16(afq, bf, acc, 0, 0, 0);
        int j = nt * 16 + lr;
        bool bad = (kmask[j] != 0);
        #pragma unroll
        for (int r = 0; r < 4; r++)
            raw[nt][r] = bad ? -1e30f : acc[r] * 0.0625f;
    }
    // write relu'd scores (cols 0..127, zero for j>=100) for MoE A operand
    #pragma unroll
    for (int nt = 0; nt < 8; nt++) {
        int j = nt * 16 + lr;
        #pragma unroll
        for (int r = 0; r < 4; r++) {
            float v = raw[nt][r];
            v = (j >= 100 || v < 0.f) ? 0.f : v;
            S[m0 + lc * 4 + r][j] = (__bf16)v;
        }
    }
    __syncthreads();   // all waves done reading Ks -> safe to overwrite with Vt

    // ---- stage V transposed into KV region (stride 200); overlaps MoE ----
    const __bf16* vbase = vg + (size_t)bh * 164 * 32;
    for (int c = tid; c < 656; c += 256) {
        int j = c >> 2, part = c & 3;
        bf16x8 val = ldb8(vbase + j * 32 + part * 8);
        #pragma unroll
        for (int u = 0; u < 8; u++) KV[(part * 8 + u) * 200 + j] = val[u];
    }
    for (int c = tid; c < 896; c += 256) {
        int d = c & 31, j = 164 + (c >> 5);
        KV[d * 200 + j] = (__bf16)0.f;
    }

    // ---- MoE: accumulate expert outputs straight into raw (rows<100 tiles) ----
    // w2t rows n>=100 are zero-padded and gtile rows >=100 are zero, so the
    // unconditional adds below are exact.
    if (rt < 2) {
        for (int e = 0; e < 4; e++) {
            // h1 = relu(reluS @ w1[e] + b1[e]); reload A-frags per expert (short live range)
            #pragma unroll
            for (int nt = 0; nt < 4; nt++) {
                f32x4 acc = {0.f, 0.f, 0.f, 0.f};
                #pragma unroll
                for (int kt = 0; kt < 4; kt++) {
                    bf16x8 sa = ldb8(&S[m0 + lr][kt * 32 + lc * 8]);
                    bf16x8 bb = ldb8(w1t + (size_t)(e * 64 + nt * 16 + lr) * 128 + kt * 32 + lc * 8);
                    acc = __builtin_amdgcn_mfma_f32_16x16x32_bf16(sa, bb, acc, 0, 0, 0);
                }
                int n = nt * 16 + lr;
                float bias = (n < 50) ? (float)b1g[e * 50 + n] : 0.f;
                #pragma unroll
                for (int r = 0; r < 4; r++) {
                    float v = acc[r] + bias;
                    if (v < 0.f) v = 0.f;
                    h1s[m0 + lc * 4 + r][n] = (__bf16)v;
                }
            }
            // eo = relu(h1 @ w2[e] + b2[e]); raw += eo * gate[:,e]
            bf16x8 ha0 = ldb8(&h1s[m0 + lr][lc * 8]);
            bf16x8 ha1 = ldb8(&h1s[m0 + lr][32 + lc * 8]);
            float gt[4];
            #pragma unroll
            for (int r = 0; r < 4; r++) gt[r] = gtile[m0 + lc * 4 + r][e];
            #pragma unroll
            for (int nt = 0; nt < 7; nt++) {
                f32x4 acc = {0.f, 0.f, 0.f, 0.f};
                bf16x8 bb0 = ldb8(w2t + (size_t)(e * 112 + nt * 16 + lr) * 64 + lc * 8);
                acc = __builtin_amdgcn_mfma_f32_16x16x32_bf16(ha0, bb0, acc, 0, 0, 0);
                bf16x8 bb1 = ldb8(w2t + (size_t)(e * 112 + nt * 16 + lr) * 64 + 32 + lc * 8);
                acc = __builtin_amdgcn_mfma_f32_16x16x32_bf16(ha1, bb1, acc, 0, 0, 0);
                int n = nt * 16 + lr;
                float bias = (n < 100) ? (float)b2g[e * 100 + n] : 0.f;
                #pragma unroll
                for (int r = 0; r < 4; r++) {
                    float v = acc[r] + bias;
                    if (v < 0.f) v = 0.f;
                    raw[nt][r] += v * gt[r];
                }
            }
        }
    }

    // ---- in-register softmax (row = m0+lc*4+r spread over lr lanes) ----
    #pragma unroll
    for (int r = 0; r < 4; r++) {
        float m2 = -3.0e38f;
        #pragma unroll
        for (int nt = 0; nt < 12; nt++) m2 = fmaxf(m2, raw[nt][r]);
        m2 = fmaxf(m2, __shfl_xor(m2, 1, 64));
        m2 = fmaxf(m2, __shfl_xor(m2, 2, 64));
        m2 = fmaxf(m2, __shfl_xor(m2, 4, 64));
        m2 = fmaxf(m2, __shfl_xor(m2, 8, 64));
        float s2 = 0.f;
        #pragma unroll
        for (int nt = 0; nt < 12; nt++) {
            float ev = __expf(raw[nt][r] - m2);
            raw[nt][r] = ev;
            s2 += ev;
        }
        s2 += __shfl_xor(s2, 1, 64);
        s2 += __shfl_xor(s2, 2, 64);
        s2 += __shfl_xor(s2, 4, 64);
        s2 += __shfl_xor(s2, 8, 64);
        float inv = (s2 > 0.f) ? 1.f / s2 : 0.f;
        #pragma unroll
        for (int nt = 0; nt < 12; nt++)
            S[m0 + lc * 4 + r][nt * 16 + lr] = (__bf16)(raw[nt][r] * inv);
    }
    __syncthreads();   // Vt staged by all threads

    // ---- O = attn @ V ----
    #pragma unroll
    for (int nt = 0; nt < 2; nt++) {
        f32x4 acc = {0.f, 0.f, 0.f, 0.f};
        #pragma unroll
        for (int kt = 0; kt < 6; kt++) {
            bf16x8 pa = ldb8(&S[m0 + lr][kt * 32 + lc * 8]);
            bf16x8 bb = ldb8(&KV[(nt * 16 + lr) * 200 + kt * 32 + lc * 8]);
            acc = __builtin_amdgcn_mfma_f32_16x16x32_bf16(pa, bb, acc, 0, 0, 0);
        }
        int d = nt * 16 + lr;
        #pragma unroll
        for (int r = 0; r < 4; r++) {
            int gi = rt * 64 + m0 + lc * 4 + r;
            if (gi < 164)
                ohg[((size_t)bh * 164 + gi) * 32 + d] = (__bf16)acc[r];
        }
    }
}

// ---------------- output projection (writes fp32) ----------------
__global__ __launch_bounds__(256) void outproj_kernel(
    const __bf16* __restrict__ oh, const __bf16* __restrict__ wot,
    const __bf16* __restrict__ wsm, float* __restrict__ out)
{
    const __bf16* bout = wsm + 740;
    const int b = blockIdx.y;
    const int mt = blockIdx.x >> 1;
    const int ntile = blockIdx.x & 1;
    const int tid = threadIdx.x;
    const int w = tid >> 6, l = tid & 63, lr = l & 15, lc = l >> 4;
    int row = mt * 64 + w * 16 + lr; if (row > 163) row = 163;
    f32x4 acc[8];
    #pragma unroll
    for (int nt = 0; nt < 8; nt++) acc[nt] = (f32x4){0.f, 0.f, 0.f, 0.f};
    #pragma unroll
    for (int kt = 0; kt < 8; kt++) {
        bf16x8 a = ldb8(oh + (((size_t)b * 8 + kt) * 164 + row) * 32 + lc * 8);
        #pragma unroll
        for (int nt = 0; nt < 8; nt++) {
            bf16x8 bb = ldb8(wot + (size_t)(ntile * 128 + nt * 16 + lr) * 256 + kt * 32 + lc * 8);
            acc[nt] = __builtin_amdgcn_mfma_f32_16x16x32_bf16(a, bb, acc[nt], 0, 0, 0);
        }
    }
    #pragma unroll
    for (int nt = 0; nt < 8; nt++) {
        int n = ntile * 128 + nt * 16 + lr;
        float bias = (float)bout[n];
        #pragma unroll
        for (int r = 0; r < 4; r++) {
            int i = mt * 64 + w * 16 + lc * 4 + r;
            if (i < 164)
                out[((size_t)b * 164 + i) * 256 + n] = acc[nt][r] + bias;
        }
    }
}

extern "C" void kernel_launch(void* const* d_in, const int* in_sizes, int n_in,
                              void* d_out, int out_size, void* d_ws, size_t ws_size,
                              hipStream_t stream) {
    const void* x      = d_in[0];
    const void* mask   = d_in[1];
    const void* w_qk_s = d_in[2];
    const void* w_qk_q = d_in[3];
    const void* w_v    = d_in[4];
    const void* w_gate = d_in[5];
    const void* b_gate = d_in[6];
    const void* ln_g   = d_in[7];
    const void* ln_b   = d_in[8];
    const void* w1     = d_in[9];
    const void* b1     = d_in[10];
    const void* w2     = d_in[11];
    const void* b2     = d_in[12];
    const void* w_out  = d_in[13];
    const void* b_out  = d_in[14];
    float* out = (float*)d_out;

    char* ws = (char*)d_ws;
    size_t off = 0;
    auto nextp = [&](size_t bytes) {
        char* p = ws + off;
        off += (bytes + 255) & ~(size_t)255;
        return p;
    };
    const size_t QKV_ELEMS = (size_t)256 * 8 * 164 * 32;   // 10,747,904
    int*    modes  = (int*)nextp(64);
    int*    maskws = (int*)nextp((size_t)41984 * 4);
    __bf16* qws  = (__bf16*)nextp(QKV_ELEMS * 2);
    __bf16* kws  = (__bf16*)nextp(QKV_ELEMS * 2);
    __bf16* vws  = (__bf16*)nextp(QKV_ELEMS * 2);
    __bf16* ohws = (__bf16*)nextp(QKV_ELEMS * 2);
    float*  gws  = (float*)nextp((size_t)2048 * 100 * 4 * 4);
    __bf16* Wts  = (__bf16*)nextp(768 * 256 * 2);
    __bf16* Wtq  = (__bf16*)nextp(768 * 256 * 2);
    __bf16* w1t  = (__bf16*)nextp(4 * 64 * 128 * 2);
    __bf16* w2t  = (__bf16*)nextp(4 * 112 * 64 * 2);
    __bf16* wot  = (__bf16*)nextp(256 * 256 * 2);
    __bf16* wsm  = (__bf16*)nextp(996 * 2);

    detect_kernel<<<1, 256, 0, stream>>>(x, mask, modes, maskws);
    prep_kernel<<<1268, 256, 0, stream>>>(w_qk_s, w_qk_q, w_v, w1, w2, w_out,
                                          w_gate, b_gate, ln_g, ln_b, b1, b2,
                                          b_out, modes, Wts, Wtq, w1t, w2t, wot, wsm);
    gate_kernel<<<2048, 128, 0, stream>>>(x, wsm, modes, gws);
    qkv_kernel<<<dim3(6, 256), 256, 0, stream>>>(x, Wts, Wtq, modes, qws, kws, vws);
    attn_kernel<<<dim3(2048, 3), 256, 0, stream>>>(qws, kws, vws, gws, maskws,
                                                   w1t, w2t, wsm, ohws);
    outproj_kernel<<<dim3(6, 256), 256, 0, stream>>>(ohws, wot, wsm, out);
}

// Round 6
// 554.720 us; speedup vs baseline: 1.3914x; 1.0845x over previous
//
#include <hip/hip_runtime.h>

typedef __bf16 bf16x8 __attribute__((ext_vector_type(8)));
typedef __bf16 bf16x4 __attribute__((ext_vector_type(4)));
typedef float  f32x4  __attribute__((ext_vector_type(4)));

__device__ __forceinline__ bf16x8 ldb8(const __bf16* p) {
    return *reinterpret_cast<const bf16x8*>(p);
}
__device__ __forceinline__ bf16x8 zero8() {
    bf16x8 z;
    #pragma unroll
    for (int i = 0; i < 8; i++) z[i] = (__bf16)0.f;
    return z;
}
// mode m: 0 = storage is bf16, 1 = storage is fp32
__device__ __forceinline__ __bf16 ldw(const void* p, int i, int m) {
    return m ? (__bf16)((const float*)p)[i] : ((const __bf16*)p)[i];
}
__device__ __forceinline__ bf16x8 ldx8(const void* p, size_t ei, int m) {
    if (m) {
        const float* f = (const float*)p + ei;
        f32x4 a = *reinterpret_cast<const f32x4*>(f);
        f32x4 b = *reinterpret_cast<const f32x4*>(f + 4);
        bf16x8 r;
        #pragma unroll
        for (int u = 0; u < 4; u++) { r[u] = (__bf16)a[u]; r[4 + u] = (__bf16)b[u]; }
        return r;
    }
    return ldb8((const __bf16*)p + ei);
}

// ---------------- detect: input dtype + mask expand (64 blocks) ----------------
__global__ __launch_bounds__(256) void detect_kernel(
    const void* x, const void* mask, int* modes, int* maskws)
{
    __shared__ int v32bad, v16bad, sbad;
    const int t = threadIdx.x, bid = blockIdx.x;
    if (t == 0) { v32bad = 0; v16bad = 0; sbad = 0; }
    __syncthreads();
    // every block recomputes the mask width locally (cheap, avoids cross-block dep)
    const unsigned int* mw = (const unsigned int*)mask;
    int b32 = 0, b16 = 0;
    for (int i = t; i < 10496; i += 256) {
        unsigned int w = mw[i];
        if (!(w == 0u || w == 1u || w == 0x3F800000u)) b32++;
        unsigned int h0 = w & 0xFFFFu, h1 = w >> 16;
        if (!(h0 == 0u || h0 == 1u || h0 == 0x3F80u)) b16++;
        if (!(h1 == 0u || h1 == 1u || h1 == 0x3F80u)) b16++;
    }
    if (b32) atomicAdd(&v32bad, b32);
    if (b16) atomicAdd(&v16bad, b16);
    if (bid == 0) {
        const unsigned int* xw = (const unsigned int*)x;
        int bad = 0;
        for (int i = t; i < 2048; i += 256) {
            unsigned int w = xw[i];
            unsigned int el = (w >> 7) & 0xFF, eh = (w >> 23) & 0xFF;
            if (el >= 0x94 || el == 0xFF) bad++;
            if (eh >= 0x94 || eh == 0xFF) bad++;
        }
        if (bad) atomicAdd(&sbad, bad);
    }
    __syncthreads();
    const int mmode = (v32bad == 0) ? 0 : ((v16bad == 0) ? 2 : 1);
    if (bid == 0 && t == 0) { modes[0] = (sbad > 64) ? 1 : 0; modes[1] = mmode; }
    const int lo = bid * 656, hi = lo + 656;   // 64*656 = 41984
    for (int i = lo + t; i < hi; i += 256) {
        int val;
        if (mmode == 0)      val = (((const int*)mask)[i] != 0);
        else if (mmode == 2) val = (((const unsigned short*)mask)[i] != 0);
        else                 val = (((const unsigned char*)mask)[i] != 0);
        maskws[i] = val;
    }
}

// ---------------- prep: transpose/pad weights into ws (mode-aware) ----------------
// Wts/Wtq: (768 x 256)  rows 0..511 = w_qk^T (q|k), rows 512..767 = w_v^T
// w1t: (4 x 64 x 128)  w1[e]^T zero-padded (n<50, k<100)
// w2t: (4 x 112 x 64)  w2[e]^T zero-padded (n<100, k<50)
// wot: (256 x 256)     w_out^T
// wsm: [0:128)=w_gate [128:132)=b_gate [132:136)=ln_g [136:140)=ln_b
//      [140:340)=b1 [340:740)=b2 [740:996)=b_out
__global__ __launch_bounds__(256) void prep_kernel(
    const void* wqks, const void* wqkq, const void* wv, const void* w1,
    const void* w2, const void* wout, const void* wg, const void* bg,
    const void* lng, const void* lnb, const void* b1, const void* b2,
    const void* bout, const int* __restrict__ modes,
    __bf16* __restrict__ Wts, __bf16* __restrict__ Wtq,
    __bf16* __restrict__ w1t, __bf16* __restrict__ w2t,
    __bf16* __restrict__ wot, __bf16* __restrict__ wsm)
{
    const int m = modes[0];
    int i = blockIdx.x * 256 + threadIdx.x;
    if (i < 196608) {
        int n = i >> 8, k = i & 255;
        __bf16 vs, vq;
        if (n < 512) { vs = ldw(wqks, k * 512 + n, m); vq = ldw(wqkq, k * 512 + n, m); }
        else         { vs = ldw(wv, k * 256 + (n - 512), m); vq = vs; }
        Wts[i] = vs; Wtq[i] = vq;
        return;
    }
    i -= 196608;
    if (i < 32768) {
        int e = i >> 13, r = i & 8191, n = r >> 7, k = r & 127;
        w1t[i] = (n < 50 && k < 100) ? ldw(w1, (e * 100 + k) * 50 + n, m) : (__bf16)0.f;
        return;
    }
    i -= 32768;
    if (i < 28672) {
        int e = i / 7168, r = i % 7168, n = r >> 6, k = r & 63;
        w2t[i] = (n < 100 && k < 50) ? ldw(w2, (e * 50 + k) * 100 + n, m) : (__bf16)0.f;
        return;
    }
    i -= 28672;
    if (i < 65536) {
        int n = i >> 8, k = i & 255;
        wot[i] = ldw(wout, k * 256 + n, m);
        return;
    }
    i -= 65536;
    if (i < 996) {
        __bf16 v;
        if (i < 128)      v = ldw(wg, i, m);
        else if (i < 132) v = ldw(bg, i - 128, m);
        else if (i < 136) v = ldw(lng, i - 132, m);
        else if (i < 140) v = ldw(lnb, i - 136, m);
        else if (i < 340) v = ldw(b1, i - 140, m);
        else if (i < 740) v = ldw(b2, i - 340, m);
        else              v = ldw(bout, i - 740, m);
        wsm[i] = v;
    }
}

// ---------------- qkv projection GEMM + fused gate ----------------
// grid (6, B). Block = 32 rows x 768 cols; x staged to LDS once.
// After staging, thread t computes gate for jg = rbase*8 + t (LN+softmax).
__global__ __launch_bounds__(256, 2) void qkv_kernel(
    const void* __restrict__ x, const __bf16* __restrict__ Wts,
    const __bf16* __restrict__ Wtq, const __bf16* __restrict__ wsm,
    const int* __restrict__ modes,
    __bf16* __restrict__ q, __bf16* __restrict__ k, __bf16* __restrict__ v,
    float* __restrict__ gates)
{
    __shared__ __bf16 xs[32][264];
    __shared__ float wgf[128];
    __shared__ float gcst[12];
    const int m = modes[0];
    const int b = blockIdx.y;
    const int mt = blockIdx.x;
    const __bf16* Wt = (mt < 4) ? Wts : Wtq;
    const int rbase = (mt < 4) ? mt * 32 : 100 + (mt - 4) * 32;
    const int tid = threadIdx.x;

    if (tid < 128) wgf[tid] = (float)wsm[tid];
    if (tid < 12)  gcst[tid] = (float)wsm[128 + tid];
    for (int c = tid; c < 1024; c += 256) {
        int row = c >> 5, part = c & 31;
        bf16x8 val = ldx8(x, ((size_t)b * 164 + rbase + row) * 256 + part * 8, m);
        *reinterpret_cast<bf16x8*>(&xs[row][part * 8]) = val;
    }
    __syncthreads();

    // ---- fused gate: jg = global 32-chunk index; h = jg/164, j = jg%164 ----
    {
        int jg = rbase * 8 + tid;         // <= 1311
        int h = jg / 164;
        int j = jg - h * 164;
        if (j < 100) {
            const __bf16* xp = &xs[tid >> 3][(tid & 7) * 32];
            float g[4] = {gcst[0], gcst[1], gcst[2], gcst[3]};
            #pragma unroll
            for (int p = 0; p < 4; p++) {
                bf16x8 xv = ldb8(xp + p * 8);
                #pragma unroll
                for (int u = 0; u < 8; u++) {
                    float f = (float)xv[u];
                    #pragma unroll
                    for (int e = 0; e < 4; e++) g[e] += f * wgf[(p * 8 + u) * 4 + e];
                }
            }
            float mu = 0.25f * (g[0] + g[1] + g[2] + g[3]);
            float var = 0.25f * ((g[0]-mu)*(g[0]-mu) + (g[1]-mu)*(g[1]-mu) +
                                 (g[2]-mu)*(g[2]-mu) + (g[3]-mu)*(g[3]-mu));
            float is = rsqrtf(var + 1e-5f);
            float mx = -3.0e38f;
            #pragma unroll
            for (int e = 0; e < 4; e++) {
                g[e] = (g[e] - mu) * is * gcst[4 + e] + gcst[8 + e];
                mx = fmaxf(mx, g[e]);
            }
            float s = 0.f;
            #pragma unroll
            for (int e = 0; e < 4; e++) { g[e] = __expf(g[e] - mx); s += g[e]; }
            float inv = 1.f / s;
            float4 gv = make_float4(g[0]*inv, g[1]*inv, g[2]*inv, g[3]*inv);
            *reinterpret_cast<float4*>(&gates[((size_t)(b * 8 + h) * 100 + j) * 4]) = gv;
        }
    }

    const int w = tid >> 6, l = tid & 63, lr = l & 15, lc = l >> 4;
    f32x4 acc[2][12];
    #pragma unroll
    for (int ms = 0; ms < 2; ms++)
        #pragma unroll
        for (int nt = 0; nt < 12; nt++) acc[ms][nt] = (f32x4){0.f, 0.f, 0.f, 0.f};

    #pragma unroll
    for (int kt = 0; kt < 8; kt++) {
        bf16x8 a0 = ldb8(&xs[lr][kt * 32 + lc * 8]);
        bf16x8 a1 = ldb8(&xs[16 + lr][kt * 32 + lc * 8]);
        #pragma unroll
        for (int nt = 0; nt < 12; nt++) {
            bf16x8 bb = ldb8(Wt + (size_t)(w * 192 + nt * 16 + lr) * 256 + kt * 32 + lc * 8);
            acc[0][nt] = __builtin_amdgcn_mfma_f32_16x16x32_bf16(a0, bb, acc[0][nt], 0, 0, 0);
            acc[1][nt] = __builtin_amdgcn_mfma_f32_16x16x32_bf16(a1, bb, acc[1][nt], 0, 0, 0);
        }
    }
    #pragma unroll
    for (int ms = 0; ms < 2; ms++) {
        #pragma unroll
        for (int nt = 0; nt < 12; nt++) {
            int c = w * 192 + nt * 16 + lr;
            __bf16* dst; int ch;
            if (c < 256)      { dst = q; ch = c; }
            else if (c < 512) { dst = k; ch = c - 256; }
            else              { dst = v; ch = c - 512; }
            int hh = ch >> 5, d = ch & 31;
            #pragma unroll
            for (int r = 0; r < 4; r++) {
                int i = rbase + ms * 16 + lc * 4 + r;
                if (mt >= 4 || i < 100)
                    dst[(((size_t)b * 8 + hh) * 164 + i) * 32 + d] = (__bf16)acc[ms][nt][r];
            }
        }
    }
}

// ---------------- fused attention v4: 4 blocks/CU, carved LDS ----------------
// LDS pool 40704 B:
//   [0)      Ks[176][40]  (QK phase)   / Vt[32][200] (PV phase)   14080 B
//   [14080)  reluS[64][136] (MoE)      \ union with
//   [31488)  h1s[64][72]   (MoE)       / P[64][200] @14080 (probs) 25600 B
__global__ __launch_bounds__(256, 4) void attn_kernel(
    const __bf16* __restrict__ qg, const __bf16* __restrict__ kg,
    const __bf16* __restrict__ vg, const float* __restrict__ gatesg,
    const int* __restrict__ maskg, const __bf16* __restrict__ w1t,
    const __bf16* __restrict__ w2t, const __bf16* __restrict__ wsm,
    __bf16* __restrict__ ohg)
{
    __shared__ __align__(16) __bf16 lds[20352];
    const int RS_OFF = 7040;     // elems
    const int H1_OFF = 15744;
    const int P_OFF  = 7040;

    const __bf16* b1g = wsm + 140;
    const __bf16* b2g = wsm + 340;
    const int bh = blockIdx.x, rt = blockIdx.y, b = bh >> 3, tid = threadIdx.x;
    const int w = tid >> 6, l = tid & 63, lr = l & 15, lc = l >> 4;
    const int m0 = w * 16;

    // ---- stage K rows 0..175 (zeros >=164), stride 40 ----
    const __bf16* kbase = kg + (size_t)bh * 164 * 32;
    for (int c = tid; c < 704; c += 256) {
        int row = c >> 2, part = c & 3;
        bf16x8 val = (row < 164) ? ldb8(kbase + row * 32 + part * 8) : zero8();
        *reinterpret_cast<bf16x8*>(&lds[row * 40 + part * 8]) = val;
    }
    // ---- per-lane key-mask bits for j = nt*16+lr, nt 0..10 ----
    unsigned mbits = 0;
    #pragma unroll
    for (int nt = 0; nt < 11; nt++) {
        int j = nt * 16 + lr;
        int bad = (j < 164) ? maskg[b * 164 + j] : 1;
        mbits |= (bad ? 1u : 0u) << nt;
    }
    __syncthreads();

    // ---- QK^T -> raw scores in registers; j>=176 constant-masked ----
    int qrow = rt * 64 + m0 + lr; if (qrow > 163) qrow = 163;
    bf16x8 afq = ldb8(qg + ((size_t)bh * 164 + qrow) * 32 + lc * 8);
    f32x4 raw[12];
    #pragma unroll
    for (int nt = 0; nt < 11; nt++) {
        bf16x8 bf = ldb8(&lds[(nt * 16 + lr) * 40 + lc * 8]);
        f32x4 acc = {0.f, 0.f, 0.f, 0.f};
        acc = __builtin_amdgcn_mfma_f32_16x16x32_bf16(afq, bf, acc, 0, 0, 0);
        bool bad = (mbits >> nt) & 1;
        #pragma unroll
        for (int r = 0; r < 4; r++)
            raw[nt][r] = bad ? -1e30f : acc[r] * 0.0625f;
    }
    #pragma unroll
    for (int r = 0; r < 4; r++) raw[11][r] = -1e30f;

    // write relu'd scores (cols 0..127, zero for j>=100), stride 136
    #pragma unroll
    for (int nt = 0; nt < 8; nt++) {
        int j = nt * 16 + lr;
        #pragma unroll
        for (int r = 0; r < 4; r++) {
            float v = raw[nt][r];
            v = (j >= 100 || v < 0.f) ? 0.f : v;
            lds[RS_OFF + (m0 + lc * 4 + r) * 136 + j] = (__bf16)v;
        }
    }
    __syncthreads();   // Ks dead -> Vt overwrites region 1

    // ---- stage V transposed, row-wise: 1 b128 LDS write per pass ----
    const __bf16* vbase = vg + (size_t)bh * 164 * 32;
    {
        int dd = tid & 31;
        #pragma unroll
        for (int p = 0; p < 3; p++) {
            int jg = (tid >> 5) + p * 8;   // 0..23 -> cols 0..191
            int j0 = jg * 8;
            bf16x8 vv = zero8();
            if (j0 < 164) {
                #pragma unroll
                for (int u = 0; u < 8; u++)
                    if (j0 + u < 164) vv[u] = vbase[(size_t)(j0 + u) * 32 + dd];
            }
            *reinterpret_cast<bf16x8*>(&lds[dd * 200 + j0]) = vv;
        }
    }

    // ---- MoE: accumulate expert outputs straight into raw (rows < 100) ----
    if (rt < 2) {
        const int gi0 = rt * 64 + m0 + lc * 4;
        for (int e = 0; e < 4; e++) {
            bf16x8 sa[4];
            #pragma unroll
            for (int kt = 0; kt < 4; kt++)
                sa[kt] = ldb8(&lds[RS_OFF + (m0 + lr) * 136 + kt * 32 + lc * 8]);
            #pragma unroll
            for (int nt = 0; nt < 4; nt++) {
                f32x4 acc = {0.f, 0.f, 0.f, 0.f};
                #pragma unroll
                for (int kt = 0; kt < 4; kt++) {
                    bf16x8 bb = ldb8(w1t + (size_t)(e * 64 + nt * 16 + lr) * 128 + kt * 32 + lc * 8);
                    acc = __builtin_amdgcn_mfma_f32_16x16x32_bf16(sa[kt], bb, acc, 0, 0, 0);
                }
                int n = nt * 16 + lr;
                float bias = (n < 50) ? (float)b1g[e * 50 + n] : 0.f;
                #pragma unroll
                for (int r = 0; r < 4; r++) {
                    float v = acc[r] + bias;
                    if (v < 0.f) v = 0.f;
                    lds[H1_OFF + (m0 + lc * 4 + r) * 72 + n] = (__bf16)v;
                }
            }
            bf16x8 ha0 = ldb8(&lds[H1_OFF + (m0 + lr) * 72 + lc * 8]);
            bf16x8 ha1 = ldb8(&lds[H1_OFF + (m0 + lr) * 72 + 32 + lc * 8]);
            float gt[4];
            #pragma unroll
            for (int r = 0; r < 4; r++) {
                int gi = gi0 + r;
                gt[r] = (gi < 100) ? gatesg[((size_t)bh * 100 + gi) * 4 + e] : 0.f;
            }
            #pragma unroll
            for (int nt = 0; nt < 7; nt++) {
                f32x4 acc = {0.f, 0.f, 0.f, 0.f};
                bf16x8 bb0 = ldb8(w2t + (size_t)(e * 112 + nt * 16 + lr) * 64 + lc * 8);
                acc = __builtin_amdgcn_mfma_f32_16x16x32_bf16(ha0, bb0, acc, 0, 0, 0);
                bf16x8 bb1 = ldb8(w2t + (size_t)(e * 112 + nt * 16 + lr) * 64 + 32 + lc * 8);
                acc = __builtin_amdgcn_mfma_f32_16x16x32_bf16(ha1, bb1, acc, 0, 0, 0);
                int n = nt * 16 + lr;
                float bias = (n < 100) ? (float)b2g[e * 100 + n] : 0.f;
                #pragma unroll
                for (int r = 0; r < 4; r++) {
                    float v = acc[r] + bias;
                    if (v < 0.f) v = 0.f;
                    raw[nt][r] += v * gt[r];
                }
            }
        }
    }
    __syncthreads();   // all waves done reading reluS/h1s -> P may overwrite

    // ---- in-register softmax; write probs P (stride 200) ----
    #pragma unroll
    for (int r = 0; r < 4; r++) {
        float m2 = -3.0e38f;
        #pragma unroll
        for (int nt = 0; nt < 12; nt++) m2 = fmaxf(m2, raw[nt][r]);
        m2 = fmaxf(m2, __shfl_xor(m2, 1, 64));
        m2 = fmaxf(m2, __shfl_xor(m2, 2, 64));
        m2 = fmaxf(m2, __shfl_xor(m2, 4, 64));
        m2 = fmaxf(m2, __shfl_xor(m2, 8, 64));
        float s2 = 0.f;
        #pragma unroll
        for (int nt = 0; nt < 12; nt++) {
            float ev = __expf(raw[nt][r] - m2);
            raw[nt][r] = ev;
            s2 += ev;
        }
        s2 += __shfl_xor(s2, 1, 64);
        s2 += __shfl_xor(s2, 2, 64);
        s2 += __shfl_xor(s2, 4, 64);
        s2 += __shfl_xor(s2, 8, 64);
        float inv = (s2 > 0.f) ? 1.f / s2 : 0.f;
        #pragma unroll
        for (int nt = 0; nt < 12; nt++)
            lds[P_OFF + (m0 + lc * 4 + r) * 200 + nt * 16 + lr] = (__bf16)(raw[nt][r] * inv);
    }
    __syncthreads();   // Vt fully staged

    // ---- O^T = V^T @ P^T : A = Vt rows (d), B = P rows (i); vector epilogue ----
    int gi = rt * 64 + m0 + lr;
    #pragma unroll
    for (int nt = 0; nt < 2; nt++) {
        f32x4 acc = {0.f, 0.f, 0.f, 0.f};
        #pragma unroll
        for (int kt = 0; kt < 6; kt++) {
            bf16x8 va = ldb8(&lds[(nt * 16 + lr) * 200 + kt * 32 + lc * 8]);
            bf16x8 pb = ldb8(&lds[P_OFF + (m0 + lr) * 200 + kt * 32 + lc * 8]);
            acc = __builtin_amdgcn_mfma_f32_16x16x32_bf16(va, pb, acc, 0, 0, 0);
        }
        if (gi < 164) {
            bf16x4 ov;
            #pragma unroll
            for (int r = 0; r < 4; r++) ov[r] = (__bf16)acc[r];
            *reinterpret_cast<bf16x4*>(&ohg[((size_t)bh * 164 + gi) * 32 + nt * 16 + lc * 4]) = ov;
        }
    }
}

// ---------------- output projection (writes fp32) ----------------
__global__ __launch_bounds__(256) void outproj_kernel(
    const __bf16* __restrict__ oh, const __bf16* __restrict__ wot,
    const __bf16* __restrict__ wsm, float* __restrict__ out)
{
    const __bf16* bout = wsm + 740;
    const int b = blockIdx.y;
    const int mt = blockIdx.x >> 1;
    const int ntile = blockIdx.x & 1;
    const int tid = threadIdx.x;
    const int w = tid >> 6, l = tid & 63, lr = l & 15, lc = l >> 4;
    int row = mt * 64 + w * 16 + lr; if (row > 163) row = 163;
    f32x4 acc[8];
    #pragma unroll
    for (int nt = 0; nt < 8; nt++) acc[nt] = (f32x4){0.f, 0.f, 0.f, 0.f};
    #pragma unroll
    for (int kt = 0; kt < 8; kt++) {
        bf16x8 a = ldb8(oh + (((size_t)b * 8 + kt) * 164 + row) * 32 + lc * 8);
        #pragma unroll
        for (int nt = 0; nt < 8; nt++) {
            bf16x8 bb = ldb8(wot + (size_t)(ntile * 128 + nt * 16 + lr) * 256 + kt * 32 + lc * 8);
            acc[nt] = __builtin_amdgcn_mfma_f32_16x16x32_bf16(a, bb, acc[nt], 0, 0, 0);
        }
    }
    #pragma unroll
    for (int nt = 0; nt < 8; nt++) {
        int n = ntile * 128 + nt * 16 + lr;
        float bias = (float)bout[n];
        #pragma unroll
        for (int r = 0; r < 4; r++) {
            int i = mt * 64 + w * 16 + lc * 4 + r;
            if (i < 164)
                out[((size_t)b * 164 + i) * 256 + n] = acc[nt][r] + bias;
        }
    }
}

extern "C" void kernel_launch(void* const* d_in, const int* in_sizes, int n_in,
                              void* d_out, int out_size, void* d_ws, size_t ws_size,
                              hipStream_t stream) {
    const void* x      = d_in[0];
    const void* mask   = d_in[1];
    const void* w_qk_s = d_in[2];
    const void* w_qk_q = d_in[3];
    const void* w_v    = d_in[4];
    const void* w_gate = d_in[5];
    const void* b_gate = d_in[6];
    const void* ln_g   = d_in[7];
    const void* ln_b   = d_in[8];
    const void* w1     = d_in[9];
    const void* b1     = d_in[10];
    const void* w2     = d_in[11];
    const void* b2     = d_in[12];
    const void* w_out  = d_in[13];
    const void* b_out  = d_in[14];
    float* out = (float*)d_out;

    char* ws = (char*)d_ws;
    size_t off = 0;
    auto nextp = [&](size_t bytes) {
        char* p = ws + off;
        off += (bytes + 255) & ~(size_t)255;
        return p;
    };
    const size_t QKV_ELEMS = (size_t)256 * 8 * 164 * 32;   // 10,747,904
    int*    modes  = (int*)nextp(64);
    int*    maskws = (int*)nextp((size_t)41984 * 4);
    __bf16* qws  = (__bf16*)nextp(QKV_ELEMS * 2);
    __bf16* kws  = (__bf16*)nextp(QKV_ELEMS * 2);
    __bf16* vws  = (__bf16*)nextp(QKV_ELEMS * 2);
    __bf16* ohws = (__bf16*)nextp(QKV_ELEMS * 2);
    float*  gws  = (float*)nextp((size_t)2048 * 100 * 4 * 4);
    __bf16* Wts  = (__bf16*)nextp(768 * 256 * 2);
    __bf16* Wtq  = (__bf16*)nextp(768 * 256 * 2);
    __bf16* w1t  = (__bf16*)nextp(4 * 64 * 128 * 2);
    __bf16* w2t  = (__bf16*)nextp(4 * 112 * 64 * 2);
    __bf16* wot  = (__bf16*)nextp(256 * 256 * 2);
    __bf16* wsm  = (__bf16*)nextp(996 * 2);

    detect_kernel<<<64, 256, 0, stream>>>(x, mask, modes, maskws);
    prep_kernel<<<1268, 256, 0, stream>>>(w_qk_s, w_qk_q, w_v, w1, w2, w_out,
                                          w_gate, b_gate, ln_g, ln_b, b1, b2,
                                          b_out, modes, Wts, Wtq, w1t, w2t, wot, wsm);
    qkv_kernel<<<dim3(6, 256), 256, 0, stream>>>(x, Wts, Wtq, wsm, modes,
                                                 qws, kws, vws, gws);
    attn_kernel<<<dim3(2048, 3), 256, 0, stream>>>(qws, kws, vws, gws, maskws,
                                                   w1t, w2t, wsm, ohws);
    outproj_kernel<<<dim3(6, 256), 256, 0, stream>>>(ohws, wot, wsm, out);
}